// Round 6
// baseline (650.085 us; speedup 1.0000x reference)
//
#include <hip/hip_runtime.h>
#include <hip/hip_bf16.h>
#include <math.h>

typedef __hip_bfloat16 bf16;
typedef __attribute__((ext_vector_type(8))) short bf16x8;   // 8 bf16 = 4 VGPR
typedef __attribute__((ext_vector_type(4))) float f32x4;

__device__ __forceinline__ float b2f(bf16 v) { return __bfloat162float(v); }
__device__ __forceinline__ bf16  f2b(float v) { return __float2bfloat16(v); }

constexpr int Bc = 2, Tc = 1024, Dc = 2048, Hc = 16, HKVc = 4, DHc = 128, Fc = 5632;
constexpr int Mr = Bc * Tc;                      // 2048 rows
constexpr int Nqkv = Hc * DHc + 2 * HKVc * DHc;  // 3072

// async 16B global->LDS (lands at wave-uniform base + lane*16)
__device__ __forceinline__ void g2l16(void* lds, const void* g) {
  __builtin_amdgcn_global_load_lds(
      (const __attribute__((address_space(1))) unsigned int*)g,
      (__attribute__((address_space(3))) unsigned int*)lds, 16, 0, 0);
}

// ------------------------------------------------------- transpose + cast ---
// src fp32 [K][N] row-major  ->  dst bf16 [N][K] row-major (B^T for MFMA GEMM)
__global__ __launch_bounds__(256) void tcast_k(const float* __restrict__ src,
                                               bf16* __restrict__ dst,
                                               int N, int K) {
  __shared__ bf16 tile[64][68];
  const int t = threadIdx.x;
  const int n0 = blockIdx.x * 64, k0 = blockIdx.y * 64;
#pragma unroll
  for (int it = 0; it < 4; ++it) {
    const int kl = it * 16 + (t >> 4);
    const int nl = (t & 15) * 4;
    float4 v = *reinterpret_cast<const float4*>(src + (size_t)(k0 + kl) * N + n0 + nl);
    tile[kl][nl]     = f2b(v.x);
    tile[kl][nl + 1] = f2b(v.y);
    tile[kl][nl + 2] = f2b(v.z);
    tile[kl][nl + 3] = f2b(v.w);
  }
  __syncthreads();
  union { uint4 u; bf16 h[8]; } o;   // 16 B
#pragma unroll
  for (int it = 0; it < 2; ++it) {
    const int nl = it * 32 + (t >> 3);
    const int kl = (t & 7) * 8;
#pragma unroll
    for (int j = 0; j < 8; ++j) o.h[j] = tile[kl + j][nl];
    *reinterpret_cast<uint4*>(dst + (size_t)(n0 + nl) * K + k0 + kl) = o.u;
  }
}

// --------------------- transpose + cast + 16-row gate/up interleave (FFN) ---
// src fp32 [2048][5632] -> w13t rows: col n of w1 -> row 32*(n>>4)+(n&15);
// col n of w3 -> +16.  (so each 256-row B-tile pairs gate/up per 16-block)
__global__ __launch_bounds__(256) void tcast_ffn(const float* __restrict__ src,
                                                 bf16* __restrict__ dst,
                                                 int off) {
  __shared__ bf16 tile[64][68];
  const int t = threadIdx.x;
  const int n0 = blockIdx.x * 64, k0 = blockIdx.y * 64;
#pragma unroll
  for (int it = 0; it < 4; ++it) {
    const int kl = it * 16 + (t >> 4);
    const int nl = (t & 15) * 4;
    float4 v = *reinterpret_cast<const float4*>(src + (size_t)(k0 + kl) * Fc + n0 + nl);
    tile[kl][nl]     = f2b(v.x);
    tile[kl][nl + 1] = f2b(v.y);
    tile[kl][nl + 2] = f2b(v.z);
    tile[kl][nl + 3] = f2b(v.w);
  }
  __syncthreads();
  union { uint4 u; bf16 h[8]; } o;   // 16 B
#pragma unroll
  for (int it = 0; it < 2; ++it) {
    const int nl = it * 32 + (t >> 3);
    const int kl = (t & 7) * 8;
#pragma unroll
    for (int j = 0; j < 8; ++j) o.h[j] = tile[kl + j][nl];
    const int n = n0 + nl;
    const int r = ((n >> 4) << 5) + (n & 15) + off;
    *reinterpret_cast<uint4*>(dst + (size_t)r * Dc + k0 + kl) = o.u;
  }
}

// ---------------------------------------------------------------- RMSNorm ---
__global__ __launch_bounds__(256) void rmsnorm_k(const float* __restrict__ x,
                                                 const float* __restrict__ w,
                                                 bf16* __restrict__ out) {
  const size_t rbase = (size_t)blockIdx.x * Dc;
  float ss = 0.f;
  for (int i = threadIdx.x; i < Dc; i += 256) {
    float v = x[rbase + i];
    ss += v * v;
  }
#pragma unroll
  for (int off = 32; off > 0; off >>= 1) ss += __shfl_down(ss, off, 64);
  __shared__ float red[4];
  const int lane = threadIdx.x & 63, wid = threadIdx.x >> 6;
  if (lane == 0) red[wid] = ss;
  __syncthreads();
  const float scale = rsqrtf((red[0] + red[1] + red[2] + red[3]) / (float)Dc + 1e-6f);
  for (int i = threadIdx.x; i < Dc; i += 256)
    out[rbase + i] = f2b(x[rbase + i] * scale * w[i]);
}

// ----------------- reduce 4 split-K partials + residual + RMSNorm (fused) ---
// xat = x + sum_z P[z];  hb = rmsnorm(xat) * w   (one pass, one block/row)
__global__ __launch_bounds__(256) void reduce4_rms(const float* __restrict__ P,
                                                   const float* __restrict__ x,
                                                   const float* __restrict__ w,
                                                   float* __restrict__ xat,
                                                   bf16* __restrict__ hb) {
  constexpr size_t PS = (size_t)Mr * Dc;
  const size_t base4 = (size_t)blockIdx.x * (Dc / 4);
  const int t = threadIdx.x;
  float4 v[2];
  float ss = 0.f;
#pragma unroll
  for (int j = 0; j < 2; ++j) {
    const size_t c4 = base4 + t + j * 256;
    float4 a = reinterpret_cast<const float4*>(x)[c4];
#pragma unroll
    for (int z = 0; z < 4; ++z) {
      float4 q = reinterpret_cast<const float4*>(P + z * PS)[c4];
      a.x += q.x; a.y += q.y; a.z += q.z; a.w += q.w;
    }
    reinterpret_cast<float4*>(xat)[c4] = a;
    ss += a.x * a.x + a.y * a.y + a.z * a.z + a.w * a.w;
    v[j] = a;
  }
#pragma unroll
  for (int off = 32; off > 0; off >>= 1) ss += __shfl_down(ss, off, 64);
  __shared__ float red[4];
  const int lane = t & 63, wid = t >> 6;
  if (lane == 0) red[wid] = ss;
  __syncthreads();
  const float scale = rsqrtf((red[0] + red[1] + red[2] + red[3]) / (float)Dc + 1e-6f);
  bf16* hrow = hb + (size_t)blockIdx.x * Dc;
#pragma unroll
  for (int j = 0; j < 2; ++j) {
    const int c = (t + j * 256) * 4;
    hrow[c]     = f2b(v[j].x * scale * w[c]);
    hrow[c + 1] = f2b(v[j].y * scale * w[c + 1]);
    hrow[c + 2] = f2b(v[j].z * scale * w[c + 2]);
    hrow[c + 3] = f2b(v[j].w * scale * w[c + 3]);
  }
}

// --------------------- reduce 4 split-K partials + residual (final output) --
__global__ __launch_bounds__(256) void reduce4_add(const float* __restrict__ P,
                                                   const float* __restrict__ res,
                                                   float* __restrict__ out) {
  constexpr size_t PS = (size_t)Mr * Dc;
  const size_t c4 = (size_t)blockIdx.x * 256 + threadIdx.x;
  float4 a = reinterpret_cast<const float4*>(res)[c4];
#pragma unroll
  for (int z = 0; z < 4; ++z) {
    float4 q = reinterpret_cast<const float4*>(P + z * PS)[c4];
    a.x += q.x; a.y += q.y; a.z += q.z; a.w += q.w;
  }
  reinterpret_cast<float4*>(out)[c4] = a;
}

// ----------------------------------------------------- MFMA GEMM (m97-ish) --
template <bool ADDRES>
__global__ __launch_bounds__(256) void gemm128(const bf16* __restrict__ A,
                                               const bf16* __restrict__ Bt,
                                               const float* __restrict__ Res,
                                               void* __restrict__ Out,
                                               int N, int K) {
  __shared__ __align__(16) bf16 As[128 * 32];
  __shared__ __align__(16) bf16 Bs[128 * 32];
  const int t = threadIdx.x;
  const int bm = blockIdx.y * 128, bn = blockIdx.x * 128;
  const int lane = t & 63, wv = t >> 6;
  const int wm = (wv & 1) * 64, wn = (wv >> 1) * 64;
  const int sr = t >> 2, sc = (t & 3) * 8;
  const bf16* ga = A + (size_t)(bm + sr) * K + sc;
  const bf16* gb = Bt + (size_t)(bn + sr) * K + sc;
  bf16* lA0 = As + sr * 32 + sc;
  bf16* lA1 = As + (64 + sr) * 32 + sc;
  bf16* lB0 = Bs + sr * 32 + sc;
  bf16* lB1 = Bs + (64 + sr) * 32 + sc;
  const size_t rstep = (size_t)64 * K;
  f32x4 acc[4][4] = {};
  const int fr = lane & 15, fko = (lane >> 4) * 8;
  for (int k0 = 0; k0 < K; k0 += 32) {
    __syncthreads();
    g2l16(lA0, ga + k0);
    g2l16(lA1, ga + rstep + k0);
    g2l16(lB0, gb + k0);
    g2l16(lB1, gb + rstep + k0);
    __syncthreads();
    bf16x8 af[4], bff[4];
#pragma unroll
    for (int i = 0; i < 4; ++i)
      af[i] = *reinterpret_cast<const bf16x8*>(As + (wm + i * 16 + fr) * 32 + fko);
#pragma unroll
    for (int j = 0; j < 4; ++j)
      bff[j] = *reinterpret_cast<const bf16x8*>(Bs + (wn + j * 16 + fr) * 32 + fko);
#pragma unroll
    for (int i = 0; i < 4; ++i)
#pragma unroll
      for (int j = 0; j < 4; ++j)
        acc[i][j] = __builtin_amdgcn_mfma_f32_16x16x32_bf16(af[i], bff[j], acc[i][j], 0, 0, 0);
  }
  const int er = (lane >> 4) * 4, ec = lane & 15;
#pragma unroll
  for (int i = 0; i < 4; ++i)
#pragma unroll
    for (int j = 0; j < 4; ++j) {
      const int row = bm + wm + i * 16 + er;
      const int col = bn + wn + j * 16 + ec;
#pragma unroll
      for (int r = 0; r < 4; ++r) {
        const size_t idx = (size_t)(row + r) * N + col;
        if (ADDRES) ((float*)Out)[idx] = Res[idx] + acc[i][j][r];
        else        ((bf16*)Out)[idx] = f2b(acc[i][j][r]);
      }
    }
}

// -------------------------- FFN 256x256 8-phase MFMA GEMM (T2+T3+T4+T5) ----
// 512 thr (8 waves, 2Mx4N), BK=64. A dbuf 2x32KB, B tribuf 3x32KB = 160KB LDS.
// Staging map (race-free): ph0-1 A(t+1); ph2-3 B(t+2); ph4-5 A(t+2);
// ph6-7 B(t+3). vmcnt(4) at ph3/ph7 (2 half-tiles slack). XOR-swizzle:
// pre-swizzled global src col + swizzled ds_read (involution, #21).
// B rows = w13t 16-interleaved gate/up -> silu pairs are lane-local.
template <int K>
__global__ __launch_bounds__(512, 2) void ffn_gemm256(const bf16* __restrict__ A,
                                                      const bf16* __restrict__ B,
                                                      bf16* __restrict__ act) {
  constexpr int NT = K / 64;     // K-tiles
  constexpr int NIT = NT / 2;    // 2 tiles per iteration
  __shared__ bf16 As[2 * 256 * 64];
  __shared__ bf16 Bs[3 * 256 * 64];
  const int tid = threadIdx.x;
  const int lane = tid & 63, wv = tid >> 6;
  const int wr = wv >> 2, wc = wv & 3;
  const int fr = lane & 15, quad = lane >> 4;
  const int swz = fr & 7;
  const int bm = blockIdx.y * 256;
  const int bn = blockIdx.x * 256;  // w13t row base (128 output cols)
  // staging coords: thread covers 2x 16B chunks of a 128x64 half-tile
  const int lrow = tid >> 3;                          // 0..63
  const int scol = ((tid & 7) ^ (lrow & 7)) * 8;      // pre-swizzled src col
  const size_t rstep = (size_t)64 * K;

  auto stageA = [&](int t, int half) {
    const int buf = (t & 1) * 16384;
    const bf16* g = A + (size_t)(bm + half * 128 + lrow) * K + t * 64 + scol;
    bf16* d = As + buf + half * 8192 + (size_t)tid * 8;
    g2l16(d, g);
    g2l16(d + 4096, g + rstep);
  };
  auto stageB = [&](int t, int half, int buf) {
    const bf16* g = B + (size_t)(bn + half * 128 + lrow) * K + t * 64 + scol;
    bf16* d = Bs + buf * 16384 + half * 8192 + (size_t)tid * 8;
    g2l16(d, g);
    g2l16(d + 4096, g + rstep);
  };

  f32x4 acc[8][4] = {};
  const int u0 = (quad ^ swz) * 8;   // ksub 0 col offset (elems); ksub1 = ^32

  // prologue: A(0), B(0)->buf0, B(1)->buf1; wait all but B(1)
  stageA(0, 0); stageA(0, 1);
  stageB(0, 0, 0); stageB(0, 1, 0);
  stageB(1, 0, 1); stageB(1, 1, 1);
  asm volatile("s_waitcnt vmcnt(4)" ::: "memory");
  __builtin_amdgcn_s_barrier();

  int rb0 = 0, rb1 = 1, sb = 2;
  for (int it = 0; it < NIT; ++it) {
    const int t1 = 2 * it + 1;
#pragma unroll
    for (int j = 0; j < 8; ++j) {
      const int bufT = (j < 4) ? 0 : 16384;
      const int bufB = ((j < 4) ? rb0 : rb1) * 16384;
      const int qr4 = ((j & 3) >> 1) * 4, qc2 = ((j & 3) & 1) * 2;
      // ---- ds-read frags for this quadrant (12 x ds_read_b128, swizzled)
      bf16x8 af[4][2], bv[2][2];
      const bf16* Ab = As + bufT + (size_t)(wr * 128 + fr) * 64;
      const bf16* Bb = Bs + bufB + (size_t)(wc * 64 + fr) * 64;
#pragma unroll
      for (int ii = 0; ii < 4; ++ii) {
        af[ii][0] = *reinterpret_cast<const bf16x8*>(Ab + (qr4 + ii) * 1024 + u0);
        af[ii][1] = *reinterpret_cast<const bf16x8*>(Ab + (qr4 + ii) * 1024 + (u0 ^ 32));
      }
#pragma unroll
      for (int jj = 0; jj < 2; ++jj) {
        bv[jj][0] = *reinterpret_cast<const bf16x8*>(Bb + (qc2 + jj) * 1024 + u0);
        bv[jj][1] = *reinterpret_cast<const bf16x8*>(Bb + (qc2 + jj) * 1024 + (u0 ^ 32));
      }
      // ---- stage one half-tile (2 x global_load_lds)
      if (j == 0)      stageA(t1, 0);
      else if (j == 1) stageA(t1, 1);
      else if (j == 2) { if (2 * it + 2 < NT) stageB(2 * it + 2, 0, sb); }
      else if (j == 3) { if (2 * it + 2 < NT) stageB(2 * it + 2, 1, sb); }
      else if (j == 4) { if (2 * it + 2 < NT) stageA(2 * it + 2, 0); }
      else if (j == 5) { if (2 * it + 2 < NT) stageA(2 * it + 2, 1); }
      else if (j == 6) { if (2 * it + 3 < NT) stageB(2 * it + 3, 0, rb0); }
      else             { if (2 * it + 3 < NT) stageB(2 * it + 3, 1, rb0); }
      __builtin_amdgcn_s_barrier();
      asm volatile("s_waitcnt lgkmcnt(0)" ::: "memory");
      __builtin_amdgcn_sched_barrier(0);
      __builtin_amdgcn_s_setprio(1);
#pragma unroll
      for (int ii = 0; ii < 4; ++ii)
#pragma unroll
        for (int jj = 0; jj < 2; ++jj) {
          acc[qr4 + ii][qc2 + jj] = __builtin_amdgcn_mfma_f32_16x16x32_bf16(
              af[ii][0], bv[jj][0], acc[qr4 + ii][qc2 + jj], 0, 0, 0);
          acc[qr4 + ii][qc2 + jj] = __builtin_amdgcn_mfma_f32_16x16x32_bf16(
              af[ii][1], bv[jj][1], acc[qr4 + ii][qc2 + jj], 0, 0, 0);
        }
      __builtin_amdgcn_s_setprio(0);
      if (j == 3) {
        if (2 * it + 2 < NT) asm volatile("s_waitcnt vmcnt(4)" ::: "memory");
        else                 asm volatile("s_waitcnt vmcnt(0)" ::: "memory");
      } else if (j == 7) {
        if (2 * it + 3 < NT)      asm volatile("s_waitcnt vmcnt(4)" ::: "memory");
        else if (2 * it + 2 < NT) asm volatile("s_waitcnt vmcnt(0)" ::: "memory");
      }
      __builtin_amdgcn_s_barrier();
    }
    const int nrb0 = sb; sb = rb1; rb1 = rb0; rb0 = nrb0;
  }

  // ---- epilogue: silu(gate)*up, pairs are lane-local (j even=gate, odd=up)
  const int er = quad * 4, ec = lane & 15;
#pragma unroll
  for (int i = 0; i < 8; ++i) {
    const int row = bm + wr * 128 + i * 16 + er;
#pragma unroll
    for (int jp = 0; jp < 2; ++jp) {
      const f32x4 g = acc[i][2 * jp], u = acc[i][2 * jp + 1];
      const int f = blockIdx.x * 128 + wc * 32 + jp * 16 + ec;
#pragma unroll
      for (int r = 0; r < 4; ++r) {
        const float sg = g[r] / (1.f + __expf(-g[r]));
        act[(size_t)(row + r) * Fc + f] = f2b(sg * u[r]);
      }
    }
  }
}

// --------------- split-K 256x256 8-phase MFMA GEMM, f32 partial epilogue ---
// Same verified schedule as ffn_gemm256; blockIdx.z picks a KSUB-slice and a
// private f32 partial image Part[z] (plain stores; reduced by consumer).
template <int KFULL, int KSUB>
__global__ __launch_bounds__(512, 2) void gemm256sk(const bf16* __restrict__ A,
                                                    const bf16* __restrict__ Bt,
                                                    float* __restrict__ Part,
                                                    int N) {
  constexpr int NT = KSUB / 64;
  constexpr int NIT = NT / 2;
  __shared__ bf16 As[2 * 256 * 64];
  __shared__ bf16 Bs[3 * 256 * 64];
  const int tid = threadIdx.x;
  const int lane = tid & 63, wv = tid >> 6;
  const int wr = wv >> 2, wc = wv & 3;
  const int fr = lane & 15, quad = lane >> 4;
  const int swz = fr & 7;
  const int bm = blockIdx.y * 256;
  const int bn = blockIdx.x * 256;
  const int kbase = blockIdx.z * KSUB;
  const int lrow = tid >> 3;
  const int scol = ((tid & 7) ^ (lrow & 7)) * 8;
  const size_t rstep = (size_t)64 * KFULL;

  auto stageA = [&](int t, int half) {
    const int buf = (t & 1) * 16384;
    const bf16* g = A + (size_t)(bm + half * 128 + lrow) * KFULL + kbase + t * 64 + scol;
    bf16* d = As + buf + half * 8192 + (size_t)tid * 8;
    g2l16(d, g);
    g2l16(d + 4096, g + rstep);
  };
  auto stageB = [&](int t, int half, int buf) {
    const bf16* g = Bt + (size_t)(bn + half * 128 + lrow) * KFULL + kbase + t * 64 + scol;
    bf16* d = Bs + buf * 16384 + half * 8192 + (size_t)tid * 8;
    g2l16(d, g);
    g2l16(d + 4096, g + rstep);
  };

  f32x4 acc[8][4] = {};
  const int u0 = (quad ^ swz) * 8;

  stageA(0, 0); stageA(0, 1);
  stageB(0, 0, 0); stageB(0, 1, 0);
  stageB(1, 0, 1); stageB(1, 1, 1);
  asm volatile("s_waitcnt vmcnt(4)" ::: "memory");
  __builtin_amdgcn_s_barrier();

  int rb0 = 0, rb1 = 1, sb = 2;
  for (int it = 0; it < NIT; ++it) {
    const int t1 = 2 * it + 1;
#pragma unroll
    for (int j = 0; j < 8; ++j) {
      const int bufT = (j < 4) ? 0 : 16384;
      const int bufB = ((j < 4) ? rb0 : rb1) * 16384;
      const int qr4 = ((j & 3) >> 1) * 4, qc2 = ((j & 3) & 1) * 2;
      bf16x8 af[4][2], bv[2][2];
      const bf16* Ab = As + bufT + (size_t)(wr * 128 + fr) * 64;
      const bf16* Bb = Bs + bufB + (size_t)(wc * 64 + fr) * 64;
#pragma unroll
      for (int ii = 0; ii < 4; ++ii) {
        af[ii][0] = *reinterpret_cast<const bf16x8*>(Ab + (qr4 + ii) * 1024 + u0);
        af[ii][1] = *reinterpret_cast<const bf16x8*>(Ab + (qr4 + ii) * 1024 + (u0 ^ 32));
      }
#pragma unroll
      for (int jj = 0; jj < 2; ++jj) {
        bv[jj][0] = *reinterpret_cast<const bf16x8*>(Bb + (qc2 + jj) * 1024 + u0);
        bv[jj][1] = *reinterpret_cast<const bf16x8*>(Bb + (qc2 + jj) * 1024 + (u0 ^ 32));
      }
      if (j == 0)      stageA(t1, 0);
      else if (j == 1) stageA(t1, 1);
      else if (j == 2) { if (2 * it + 2 < NT) stageB(2 * it + 2, 0, sb); }
      else if (j == 3) { if (2 * it + 2 < NT) stageB(2 * it + 2, 1, sb); }
      else if (j == 4) { if (2 * it + 2 < NT) stageA(2 * it + 2, 0); }
      else if (j == 5) { if (2 * it + 2 < NT) stageA(2 * it + 2, 1); }
      else if (j == 6) { if (2 * it + 3 < NT) stageB(2 * it + 3, 0, rb0); }
      else             { if (2 * it + 3 < NT) stageB(2 * it + 3, 1, rb0); }
      __builtin_amdgcn_s_barrier();
      asm volatile("s_waitcnt lgkmcnt(0)" ::: "memory");
      __builtin_amdgcn_sched_barrier(0);
      __builtin_amdgcn_s_setprio(1);
#pragma unroll
      for (int ii = 0; ii < 4; ++ii)
#pragma unroll
        for (int jj = 0; jj < 2; ++jj) {
          acc[qr4 + ii][qc2 + jj] = __builtin_amdgcn_mfma_f32_16x16x32_bf16(
              af[ii][0], bv[jj][0], acc[qr4 + ii][qc2 + jj], 0, 0, 0);
          acc[qr4 + ii][qc2 + jj] = __builtin_amdgcn_mfma_f32_16x16x32_bf16(
              af[ii][1], bv[jj][1], acc[qr4 + ii][qc2 + jj], 0, 0, 0);
        }
      __builtin_amdgcn_s_setprio(0);
      if (j == 3) {
        if (2 * it + 2 < NT) asm volatile("s_waitcnt vmcnt(4)" ::: "memory");
        else                 asm volatile("s_waitcnt vmcnt(0)" ::: "memory");
      } else if (j == 7) {
        if (2 * it + 3 < NT)      asm volatile("s_waitcnt vmcnt(4)" ::: "memory");
        else if (2 * it + 2 < NT) asm volatile("s_waitcnt vmcnt(0)" ::: "memory");
      }
      __builtin_amdgcn_s_barrier();
    }
    const int nrb0 = sb; sb = rb1; rb1 = rb0; rb0 = nrb0;
  }

  float* P = Part + (size_t)blockIdx.z * ((size_t)Mr * N);
  const int er = quad * 4, ec = lane & 15;
#pragma unroll
  for (int i = 0; i < 8; ++i) {
    const int row = bm + wr * 128 + i * 16 + er;
#pragma unroll
    for (int jc = 0; jc < 4; ++jc) {
      const int col = bn + wc * 64 + jc * 16 + ec;
#pragma unroll
      for (int r = 0; r < 4; ++r)
        P[(size_t)(row + r) * N + col] = acc[i][jc][r];
    }
  }
}

// ---------------------------------------------- repack: RoPE + Q/K/V split --
// qkv packed [M][3072] -> Qr[B,H,T,DH], Kr[B,HKV,T,DH] (RoPE'd), Vt[B,HKV,DH,T]
__global__ __launch_bounds__(256) void repack_k(const bf16* __restrict__ qkv,
                                                const float* __restrict__ cosb,
                                                const float* __restrict__ sinb,
                                                bf16* __restrict__ Qr,
                                                bf16* __restrict__ Kr,
                                                bf16* __restrict__ Vt) {
  const int bt = blockIdx.x;
  const int b = bt >> 10, tp = bt & (Tc - 1);
  const int t0 = threadIdx.x;
  const bf16* row = qkv + (size_t)bt * Nqkv;
#pragma unroll
  for (int k = 0; k < 4; ++k) {      // Q: 1024 rope pairs
    int p2 = k * 256 + t0;
    int hh = p2 >> 6, i = p2 & 63;
    float c = cosb[tp * 64 + i], sn = sinb[tp * 64 + i];
    float x0 = b2f(row[hh * 128 + 2 * i]), x1 = b2f(row[hh * 128 + 2 * i + 1]);
    bf16* dst = Qr + ((size_t)(b * Hc + hh) * Tc + tp) * DHc + 2 * i;
    dst[0] = f2b(x0 * c - x1 * sn);
    dst[1] = f2b(x0 * sn + x1 * c);
  }
  {                                   // K: 256 rope pairs
    int hh = t0 >> 6, i = t0 & 63;
    float c = cosb[tp * 64 + i], sn = sinb[tp * 64 + i];
    float x0 = b2f(row[2048 + hh * 128 + 2 * i]), x1 = b2f(row[2048 + hh * 128 + 2 * i + 1]);
    bf16* dst = Kr + ((size_t)(b * HKVc + hh) * Tc + tp) * DHc + 2 * i;
    dst[0] = f2b(x0 * c - x1 * sn);
    dst[1] = f2b(x0 * sn + x1 * c);
  }
#pragma unroll
  for (int k = 0; k < 2; ++k) {      // V: 512 elems, transposed store
    int e = k * 256 + t0;
    int kvh = e >> 7, dd = e & 127;
    Vt[((size_t)(b * HKVc + kvh) * DHc + dd) * Tc + tp] = row[2560 + e];
  }
}

// ----------------------------------------------------- MFMA flash attention --
// block = (b, h, 64-row q-tile); 4 INDEPENDENT waves x 16 q-rows; 64-key tiles.
// K/V read directly from global (L2-resident: 512KB/group, 4MB total) —
// no LDS staging, ZERO barriers (m169: staging L2-fit data is pure overhead).
// Only P bounces through per-wave LDS (layout shuffle C->A frag).
__global__ __launch_bounds__(256) void fattn(const bf16* __restrict__ Qr,
                                             const bf16* __restrict__ Kr,
                                             const bf16* __restrict__ Vt,
                                             bf16* __restrict__ ao) {
  __shared__ __align__(16) bf16 Ps[4][16 * 72];  // per-wave P
  const int idx = blockIdx.x;
  const int r = idx & 15;
  const int qt = (r & 1) ? (15 - (r >> 1)) : (r >> 1);  // pair-balanced
  const int h = (idx >> 4) & 15;
  const int b = idx >> 8;
  const int kv = h >> 2;
  const int t = threadIdx.x, lane = t & 63, wv = t >> 6;
  const int fr = lane & 15, quad = lane >> 4;

  const bf16* Qbase = Qr + ((size_t)(b * Hc + h) * Tc + qt * 64) * DHc;
  const bf16* Kbase = Kr + (size_t)(b * HKVc + kv) * Tc * DHc;
  const bf16* Vbase = Vt + (size_t)(b * HKVc + kv) * DHc * Tc;

  bf16x8 qf[4];
#pragma unroll
  for (int c = 0; c < 4; ++c)
    qf[c] = *reinterpret_cast<const bf16x8*>(Qbase + (size_t)(wv * 16 + fr) * DHc + c * 32 + quad * 8);

  float m[4], l[4];
  f32x4 o[8] = {};
#pragma unroll
  for (int r2 = 0; r2 < 4; ++r2) { m[r2] = -3.0e38f; l[r2] = 0.f; }

  for (int kt = 0; kt <= qt; ++kt) {
    const bf16* Kt = Kbase + (size_t)kt * 64 * DHc;
    const bf16* Vtt = Vbase + kt * 64;
    // S = Q K^T  (16 MFMA, K frags straight from global/L2)
    f32x4 s[4];
    __builtin_amdgcn_s_setprio(1);
#pragma unroll
    for (int cb = 0; cb < 4; ++cb) {
      f32x4 acc = {};
#pragma unroll
      for (int kc = 0; kc < 4; ++kc) {
        bf16x8 kf = *reinterpret_cast<const bf16x8*>(Kt + (size_t)(cb * 16 + fr) * DHc + kc * 32 + quad * 8);
        acc = __builtin_amdgcn_mfma_f32_16x16x32_bf16(qf[kc], kf, acc, 0, 0, 0);
      }
      s[cb] = acc * 0.08838834764831845f;
    }
    __builtin_amdgcn_s_setprio(0);
    if (kt == qt) {  // causal mask, diagonal tile only
#pragma unroll
      for (int cb = 0; cb < 4; ++cb)
#pragma unroll
        for (int r2 = 0; r2 < 4; ++r2) {
          int key = cb * 16 + fr;
          int qg = wv * 16 + quad * 4 + r2;
          if (key > qg) s[cb][r2] = -3.0e38f;
        }
    }
    // online softmax
    float tm[4], ts[4];
#pragma unroll
    for (int r2 = 0; r2 < 4; ++r2)
      tm[r2] = fmaxf(fmaxf(s[0][r2], s[1][r2]), fmaxf(s[2][r2], s[3][r2]));
#pragma unroll
    for (int off = 1; off < 16; off <<= 1)
#pragma unroll
      for (int r2 = 0; r2 < 4; ++r2)
        tm[r2] = fmaxf(tm[r2], __shfl_xor(tm[r2], off, 64));
    float al[4];
#pragma unroll
    for (int r2 = 0; r2 < 4; ++r2) {
      float mn = fmaxf(m[r2], tm[r2]);
      al[r2] = __expf(m[r2] - mn);
      m[r2] = mn;
      ts[r2] = 0.f;
    }
#pragma unroll
    for (int cb = 0; cb < 4; ++cb)
#pragma unroll
      for (int r2 = 0; r2 < 4; ++r2) {
        float e = __expf(s[cb][r2] - m[r2]);
        s[cb][r2] = e;
        ts[r2] += e;
      }
#pragma unroll
    for (int off = 1; off < 16; off <<= 1)
#pragma unroll
      for (int r2 = 0; r2 < 4; ++r2)
        ts[r2] += __shfl_xor(ts[r2], off, 64);
#pragma unroll
    for (int r2 = 0; r2 < 4; ++r2) l[r2] = l[r2] * al[r2] + ts[r2];
#pragma unroll
    for (int db = 0; db < 8; ++db)
#pragma unroll
      for (int r2 = 0; r2 < 4; ++r2) o[db][r2] *= al[r2];
    // P: C-layout regs -> per-wave LDS -> A-layout frags (no cross-wave sync)
    bf16* pw = Ps[wv];
#pragma unroll
    for (int cb = 0; cb < 4; ++cb)
#pragma unroll
      for (int r2 = 0; r2 < 4; ++r2)
        pw[(quad * 4 + r2) * 72 + cb * 16 + fr] = f2b(s[cb][r2]);
    bf16x8 pa[2];
    pa[0] = *reinterpret_cast<const bf16x8*>(&pw[fr * 72 + quad * 8]);
    pa[1] = *reinterpret_cast<const bf16x8*>(&pw[fr * 72 + 32 + quad * 8]);
    // O += P V  (16 MFMA, V frags straight from global/L2: Vt is [d][key])
    __builtin_amdgcn_s_setprio(1);
#pragma unroll
    for (int db = 0; db < 8; ++db) {
      bf16x8 v0 = *reinterpret_cast<const bf16x8*>(Vtt + (size_t)(db * 16 + fr) * Tc + quad * 8);
      bf16x8 v1 = *reinterpret_cast<const bf16x8*>(Vtt + (size_t)(db * 16 + fr) * Tc + 32 + quad * 8);
      o[db] = __builtin_amdgcn_mfma_f32_16x16x32_bf16(pa[0], v0, o[db], 0, 0, 0);
      o[db] = __builtin_amdgcn_mfma_f32_16x16x32_bf16(pa[1], v1, o[db], 0, 0, 0);
    }
    __builtin_amdgcn_s_setprio(0);
  }
#pragma unroll
  for (int r2 = 0; r2 < 4; ++r2) {
    float inv = 1.f / l[r2];
    int qg = qt * 64 + wv * 16 + quad * 4 + r2;
    bf16* orow = ao + (size_t)(b * Tc + qg) * Dc + h * DHc;
#pragma unroll
    for (int db = 0; db < 8; ++db)
      orow[db * 16 + fr] = f2b(o[db][r2] * inv);
  }
}

// ------------------------------------------------------------------ launch --
extern "C" void kernel_launch(void* const* d_in, const int* in_sizes, int n_in,
                              void* d_out, int out_size, void* d_ws, size_t ws_size,
                              hipStream_t stream) {
  const float* x    = (const float*)d_in[0];
  const float* fcos = (const float*)d_in[1];
  const float* fsin = (const float*)d_in[2];
  const float* wn1  = (const float*)d_in[3];
  const float* wn2  = (const float*)d_in[4];
  const float* wq   = (const float*)d_in[5];
  const float* wk   = (const float*)d_in[6];
  const float* wv   = (const float*)d_in[7];
  const float* wo   = (const float*)d_in[8];
  const float* w1   = (const float*)d_in[9];
  const float* w2   = (const float*)d_in[10];
  const float* w3   = (const float*)d_in[11];

  char* p = (char*)d_ws;
  bf16* wqkv_t = (bf16*)p;                 p += (size_t)Nqkv * Dc * 2;   // 12.58 MB
  bf16* qkv    = (bf16*)p;                 p += (size_t)Mr * Nqkv * 2;   // 12.58 MB
  float* xat   = (float*)d_ws;             // aliases wqkv_t+qkv (dead by wo-gemm)
  bf16* wo_t = (bf16*)p;                   p += (size_t)Dc * Dc * 2;     // 8.39 MB
  bf16* w13t = (bf16*)p;                   p += (size_t)2 * Fc * Dc * 2; // 46.14 MB
  bf16* w2t  = w13t;                       // aliases w13t (dead after ffn)
  bf16* xn   = (bf16*)p;                   p += (size_t)Mr * Dc * 2;     // 8.39 MB (reused as h)
  bf16* ao   = (bf16*)p;                   p += (size_t)Mr * Dc * 2;     // 8.39 MB
  bf16* act  = (bf16*)p;                   p += (size_t)Mr * Fc * 2;     // 23.07 MB
  float* Pbuf = (float*)p;                 p += (size_t)4 * Mr * Dc * 4; // 67.11 MB
  bf16* hb = xn;
  // Qr/Kr/Vt alias the act region (act written only after attention is done)
  bf16* Qr = act;                                        // 8.39 MB
  bf16* Kr = act + (size_t)Mr * Hc * DHc;                // 2.10 MB
  bf16* Vtb = Kr + (size_t)Mr * HKVc * DHc;              // 2.10 MB

  const dim3 blk(256);
  tcast_k<<<dim3(32, 32), blk, 0, stream>>>(wq, wqkv_t, 2048, 2048);
  tcast_k<<<dim3(8, 32), blk, 0, stream>>>(wk, wqkv_t + (size_t)2048 * 2048, 512, 2048);
  tcast_k<<<dim3(8, 32), blk, 0, stream>>>(wv, wqkv_t + (size_t)2560 * 2048, 512, 2048);
  tcast_k<<<dim3(32, 32), blk, 0, stream>>>(wo, wo_t, 2048, 2048);
  tcast_ffn<<<dim3(88, 32), blk, 0, stream>>>(w1, w13t, 0);
  tcast_ffn<<<dim3(88, 32), blk, 0, stream>>>(w3, w13t, 16);

  rmsnorm_k<<<Mr, blk, 0, stream>>>(x, wn1, xn);
  gemm128<false><<<dim3(Nqkv / 128, Mr / 128), blk, 0, stream>>>(xn, wqkv_t, nullptr, qkv, Nqkv, Dc);
  repack_k<<<Mr, blk, 0, stream>>>(qkv, fcos, fsin, Qr, Kr, Vtb);
  fattn<<<Bc * Hc * 16, blk, 0, stream>>>(Qr, Kr, Vtb, ao);
  // wo GEMM: partials = ao @ wo (split-K, plain f32 stores)
  gemm256sk<Dc, 512><<<dim3(Dc / 256, Mr / 256, 4), dim3(512), 0, stream>>>(ao, wo_t, Pbuf, Dc);
  // fused: xat = x + sum(partials); hb = rmsnorm(xat) * wn2
  reduce4_rms<<<Mr, blk, 0, stream>>>(Pbuf, x, wn2, xat, hb);
  ffn_gemm256<Dc><<<dim3(2 * Fc / 256, Mr / 256), dim3(512), 0, stream>>>(hb, w13t, act);
  tcast_k<<<dim3(32, 88), blk, 0, stream>>>(w2, w2t, 2048, 5632);
  // w2 GEMM: partials = act @ w2 (split-K); d_out = xat + sum(partials)
  gemm256sk<Fc, 1408><<<dim3(Dc / 256, Mr / 256, 4), dim3(512), 0, stream>>>(act, w2t, Pbuf, Dc);
  reduce4_add<<<Mr * Dc / 1024, blk, 0, stream>>>(Pbuf, xat, (float*)d_out);
}

// Round 7
// 564.308 us; speedup vs baseline: 1.1520x; 1.1520x over previous
//
#include <hip/hip_runtime.h>
#include <hip/hip_bf16.h>
#include <math.h>

typedef __hip_bfloat16 bf16;
typedef __attribute__((ext_vector_type(8))) short bf16x8;   // 8 bf16 = 4 VGPR
typedef __attribute__((ext_vector_type(4))) float f32x4;

__device__ __forceinline__ float b2f(bf16 v) { return __bfloat162float(v); }
__device__ __forceinline__ bf16  f2b(float v) { return __float2bfloat16(v); }

constexpr int Bc = 2, Tc = 1024, Dc = 2048, Hc = 16, HKVc = 4, DHc = 128, Fc = 5632;
constexpr int Mr = Bc * Tc;                      // 2048 rows
constexpr int Nqkv = Hc * DHc + 2 * HKVc * DHc;  // 3072

// async 16B global->LDS (lands at wave-uniform base + lane*16)
__device__ __forceinline__ void g2l16(void* lds, const void* g) {
  __builtin_amdgcn_global_load_lds(
      (const __attribute__((address_space(1))) unsigned int*)g,
      (__attribute__((address_space(3))) unsigned int*)lds, 16, 0, 0);
}

// ------------------------------------------------------- transpose + cast ---
// src fp32 [K][N] row-major  ->  dst bf16 [N][K] row-major (B^T for MFMA GEMM)
__global__ __launch_bounds__(256) void tcast_k(const float* __restrict__ src,
                                               bf16* __restrict__ dst,
                                               int N, int K) {
  __shared__ bf16 tile[64][68];
  const int t = threadIdx.x;
  const int n0 = blockIdx.x * 64, k0 = blockIdx.y * 64;
#pragma unroll
  for (int it = 0; it < 4; ++it) {
    const int kl = it * 16 + (t >> 4);
    const int nl = (t & 15) * 4;
    float4 v = *reinterpret_cast<const float4*>(src + (size_t)(k0 + kl) * N + n0 + nl);
    tile[kl][nl]     = f2b(v.x);
    tile[kl][nl + 1] = f2b(v.y);
    tile[kl][nl + 2] = f2b(v.z);
    tile[kl][nl + 3] = f2b(v.w);
  }
  __syncthreads();
  union { uint4 u; bf16 h[8]; } o;   // 16 B
#pragma unroll
  for (int it = 0; it < 2; ++it) {
    const int nl = it * 32 + (t >> 3);
    const int kl = (t & 7) * 8;
#pragma unroll
    for (int j = 0; j < 8; ++j) o.h[j] = tile[kl + j][nl];
    *reinterpret_cast<uint4*>(dst + (size_t)(n0 + nl) * K + k0 + kl) = o.u;
  }
}

// --------------------- transpose + cast + 16-row gate/up interleave (FFN) ---
// src fp32 [2048][5632] -> w13t rows: col n of w1 -> row 32*(n>>4)+(n&15);
// col n of w3 -> +16.  (so each 256-row B-tile pairs gate/up per 16-block)
__global__ __launch_bounds__(256) void tcast_ffn(const float* __restrict__ src,
                                                 bf16* __restrict__ dst,
                                                 int off) {
  __shared__ bf16 tile[64][68];
  const int t = threadIdx.x;
  const int n0 = blockIdx.x * 64, k0 = blockIdx.y * 64;
#pragma unroll
  for (int it = 0; it < 4; ++it) {
    const int kl = it * 16 + (t >> 4);
    const int nl = (t & 15) * 4;
    float4 v = *reinterpret_cast<const float4*>(src + (size_t)(k0 + kl) * Fc + n0 + nl);
    tile[kl][nl]     = f2b(v.x);
    tile[kl][nl + 1] = f2b(v.y);
    tile[kl][nl + 2] = f2b(v.z);
    tile[kl][nl + 3] = f2b(v.w);
  }
  __syncthreads();
  union { uint4 u; bf16 h[8]; } o;   // 16 B
#pragma unroll
  for (int it = 0; it < 2; ++it) {
    const int nl = it * 32 + (t >> 3);
    const int kl = (t & 7) * 8;
#pragma unroll
    for (int j = 0; j < 8; ++j) o.h[j] = tile[kl + j][nl];
    const int n = n0 + nl;
    const int r = ((n >> 4) << 5) + (n & 15) + off;
    *reinterpret_cast<uint4*>(dst + (size_t)r * Dc + k0 + kl) = o.u;
  }
}

// ---------------------------------------------------------------- RMSNorm ---
__global__ __launch_bounds__(256) void rmsnorm_k(const float* __restrict__ x,
                                                 const float* __restrict__ w,
                                                 bf16* __restrict__ out) {
  const size_t rbase = (size_t)blockIdx.x * Dc;
  float ss = 0.f;
  for (int i = threadIdx.x; i < Dc; i += 256) {
    float v = x[rbase + i];
    ss += v * v;
  }
#pragma unroll
  for (int off = 32; off > 0; off >>= 1) ss += __shfl_down(ss, off, 64);
  __shared__ float red[4];
  const int lane = threadIdx.x & 63, wid = threadIdx.x >> 6;
  if (lane == 0) red[wid] = ss;
  __syncthreads();
  const float scale = rsqrtf((red[0] + red[1] + red[2] + red[3]) / (float)Dc + 1e-6f);
  for (int i = threadIdx.x; i < Dc; i += 256)
    out[rbase + i] = f2b(x[rbase + i] * scale * w[i]);
}

// ----------------- reduce 4 split-K partials + residual + RMSNorm (fused) ---
// xat = x + sum_z P[z];  hb = rmsnorm(xat) * w   (one pass, one block/row)
__global__ __launch_bounds__(256) void reduce4_rms(const float* __restrict__ P,
                                                   const float* __restrict__ x,
                                                   const float* __restrict__ w,
                                                   float* __restrict__ xat,
                                                   bf16* __restrict__ hb) {
  constexpr size_t PS = (size_t)Mr * Dc;
  const size_t base4 = (size_t)blockIdx.x * (Dc / 4);
  const int t = threadIdx.x;
  float4 v[2];
  float ss = 0.f;
#pragma unroll
  for (int j = 0; j < 2; ++j) {
    const size_t c4 = base4 + t + j * 256;
    float4 a = reinterpret_cast<const float4*>(x)[c4];
#pragma unroll
    for (int z = 0; z < 4; ++z) {
      float4 q = reinterpret_cast<const float4*>(P + z * PS)[c4];
      a.x += q.x; a.y += q.y; a.z += q.z; a.w += q.w;
    }
    reinterpret_cast<float4*>(xat)[c4] = a;
    ss += a.x * a.x + a.y * a.y + a.z * a.z + a.w * a.w;
    v[j] = a;
  }
#pragma unroll
  for (int off = 32; off > 0; off >>= 1) ss += __shfl_down(ss, off, 64);
  __shared__ float red[4];
  const int lane = t & 63, wid = t >> 6;
  if (lane == 0) red[wid] = ss;
  __syncthreads();
  const float scale = rsqrtf((red[0] + red[1] + red[2] + red[3]) / (float)Dc + 1e-6f);
  bf16* hrow = hb + (size_t)blockIdx.x * Dc;
#pragma unroll
  for (int j = 0; j < 2; ++j) {
    const int c = (t + j * 256) * 4;
    hrow[c]     = f2b(v[j].x * scale * w[c]);
    hrow[c + 1] = f2b(v[j].y * scale * w[c + 1]);
    hrow[c + 2] = f2b(v[j].z * scale * w[c + 2]);
    hrow[c + 3] = f2b(v[j].w * scale * w[c + 3]);
  }
}

// --------------------- reduce 4 split-K partials + residual (final output) --
__global__ __launch_bounds__(256) void reduce4_add(const float* __restrict__ P,
                                                   const float* __restrict__ res,
                                                   float* __restrict__ out) {
  constexpr size_t PS = (size_t)Mr * Dc;
  const size_t c4 = (size_t)blockIdx.x * 256 + threadIdx.x;
  float4 a = reinterpret_cast<const float4*>(res)[c4];
#pragma unroll
  for (int z = 0; z < 4; ++z) {
    float4 q = reinterpret_cast<const float4*>(P + z * PS)[c4];
    a.x += q.x; a.y += q.y; a.z += q.z; a.w += q.w;
  }
  reinterpret_cast<float4*>(out)[c4] = a;
}

// -------------------------- FFN 256x256 8-phase MFMA GEMM (T2+T3+T4+T5) ----
// 512 thr (8 waves, 2Mx4N), BK=64. A dbuf 2x32KB, B tribuf 3x32KB = 160KB LDS.
// Staging map (race-free): ph0-1 A(t+1); ph2-3 B(t+2); ph4-5 A(t+2);
// ph6-7 B(t+3). vmcnt(4) at ph3/ph7 (2 half-tiles slack). XOR-swizzle:
// pre-swizzled global src col + swizzled ds_read (involution, #21).
// B rows = w13t 16-interleaved gate/up -> silu pairs are lane-local.
template <int K>
__global__ __launch_bounds__(512, 2) void ffn_gemm256(const bf16* __restrict__ A,
                                                      const bf16* __restrict__ B,
                                                      bf16* __restrict__ act) {
  constexpr int NT = K / 64;     // K-tiles
  constexpr int NIT = NT / 2;    // 2 tiles per iteration
  __shared__ bf16 As[2 * 256 * 64];
  __shared__ bf16 Bs[3 * 256 * 64];
  const int tid = threadIdx.x;
  const int lane = tid & 63, wv = tid >> 6;
  const int wr = wv >> 2, wc = wv & 3;
  const int fr = lane & 15, quad = lane >> 4;
  const int swz = fr & 7;
  const int bm = blockIdx.y * 256;
  const int bn = blockIdx.x * 256;  // w13t row base (128 output cols)
  // staging coords: thread covers 2x 16B chunks of a 128x64 half-tile
  const int lrow = tid >> 3;                          // 0..63
  const int scol = ((tid & 7) ^ (lrow & 7)) * 8;      // pre-swizzled src col
  const size_t rstep = (size_t)64 * K;

  auto stageA = [&](int t, int half) {
    const int buf = (t & 1) * 16384;
    const bf16* g = A + (size_t)(bm + half * 128 + lrow) * K + t * 64 + scol;
    bf16* d = As + buf + half * 8192 + (size_t)tid * 8;
    g2l16(d, g);
    g2l16(d + 4096, g + rstep);
  };
  auto stageB = [&](int t, int half, int buf) {
    const bf16* g = B + (size_t)(bn + half * 128 + lrow) * K + t * 64 + scol;
    bf16* d = Bs + buf * 16384 + half * 8192 + (size_t)tid * 8;
    g2l16(d, g);
    g2l16(d + 4096, g + rstep);
  };

  f32x4 acc[8][4] = {};
  const int u0 = (quad ^ swz) * 8;   // ksub 0 col offset (elems); ksub1 = ^32

  // prologue: A(0), B(0)->buf0, B(1)->buf1; wait all but B(1)
  stageA(0, 0); stageA(0, 1);
  stageB(0, 0, 0); stageB(0, 1, 0);
  stageB(1, 0, 1); stageB(1, 1, 1);
  asm volatile("s_waitcnt vmcnt(4)" ::: "memory");
  __builtin_amdgcn_s_barrier();

  int rb0 = 0, rb1 = 1, sb = 2;
  for (int it = 0; it < NIT; ++it) {
    const int t1 = 2 * it + 1;
#pragma unroll
    for (int j = 0; j < 8; ++j) {
      const int bufT = (j < 4) ? 0 : 16384;
      const int bufB = ((j < 4) ? rb0 : rb1) * 16384;
      const int qr4 = ((j & 3) >> 1) * 4, qc2 = ((j & 3) & 1) * 2;
      // ---- ds-read frags for this quadrant (12 x ds_read_b128, swizzled)
      bf16x8 af[4][2], bv[2][2];
      const bf16* Ab = As + bufT + (size_t)(wr * 128 + fr) * 64;
      const bf16* Bb = Bs + bufB + (size_t)(wc * 64 + fr) * 64;
#pragma unroll
      for (int ii = 0; ii < 4; ++ii) {
        af[ii][0] = *reinterpret_cast<const bf16x8*>(Ab + (qr4 + ii) * 1024 + u0);
        af[ii][1] = *reinterpret_cast<const bf16x8*>(Ab + (qr4 + ii) * 1024 + (u0 ^ 32));
      }
#pragma unroll
      for (int jj = 0; jj < 2; ++jj) {
        bv[jj][0] = *reinterpret_cast<const bf16x8*>(Bb + (qc2 + jj) * 1024 + u0);
        bv[jj][1] = *reinterpret_cast<const bf16x8*>(Bb + (qc2 + jj) * 1024 + (u0 ^ 32));
      }
      // ---- stage one half-tile (2 x global_load_lds)
      if (j == 0)      stageA(t1, 0);
      else if (j == 1) stageA(t1, 1);
      else if (j == 2) { if (2 * it + 2 < NT) stageB(2 * it + 2, 0, sb); }
      else if (j == 3) { if (2 * it + 2 < NT) stageB(2 * it + 2, 1, sb); }
      else if (j == 4) { if (2 * it + 2 < NT) stageA(2 * it + 2, 0); }
      else if (j == 5) { if (2 * it + 2 < NT) stageA(2 * it + 2, 1); }
      else if (j == 6) { if (2 * it + 3 < NT) stageB(2 * it + 3, 0, rb0); }
      else             { if (2 * it + 3 < NT) stageB(2 * it + 3, 1, rb0); }
      __builtin_amdgcn_s_barrier();
      asm volatile("s_waitcnt lgkmcnt(0)" ::: "memory");
      __builtin_amdgcn_sched_barrier(0);
      __builtin_amdgcn_s_setprio(1);
#pragma unroll
      for (int ii = 0; ii < 4; ++ii)
#pragma unroll
        for (int jj = 0; jj < 2; ++jj) {
          acc[qr4 + ii][qc2 + jj] = __builtin_amdgcn_mfma_f32_16x16x32_bf16(
              af[ii][0], bv[jj][0], acc[qr4 + ii][qc2 + jj], 0, 0, 0);
          acc[qr4 + ii][qc2 + jj] = __builtin_amdgcn_mfma_f32_16x16x32_bf16(
              af[ii][1], bv[jj][1], acc[qr4 + ii][qc2 + jj], 0, 0, 0);
        }
      __builtin_amdgcn_s_setprio(0);
      if (j == 3) {
        if (2 * it + 2 < NT) asm volatile("s_waitcnt vmcnt(4)" ::: "memory");
        else                 asm volatile("s_waitcnt vmcnt(0)" ::: "memory");
      } else if (j == 7) {
        if (2 * it + 3 < NT)      asm volatile("s_waitcnt vmcnt(4)" ::: "memory");
        else if (2 * it + 2 < NT) asm volatile("s_waitcnt vmcnt(0)" ::: "memory");
      }
      __builtin_amdgcn_s_barrier();
    }
    const int nrb0 = sb; sb = rb1; rb1 = rb0; rb0 = nrb0;
  }

  // ---- epilogue: silu(gate)*up, pairs are lane-local (j even=gate, odd=up)
  const int er = quad * 4, ec = lane & 15;
#pragma unroll
  for (int i = 0; i < 8; ++i) {
    const int row = bm + wr * 128 + i * 16 + er;
#pragma unroll
    for (int jp = 0; jp < 2; ++jp) {
      const f32x4 g = acc[i][2 * jp], u = acc[i][2 * jp + 1];
      const int f = blockIdx.x * 128 + wc * 32 + jp * 16 + ec;
#pragma unroll
      for (int r = 0; r < 4; ++r) {
        const float sg = g[r] / (1.f + __expf(-g[r]));
        act[(size_t)(row + r) * Fc + f] = f2b(sg * u[r]);
      }
    }
  }
}

// --------------- split-K 256x256 8-phase MFMA GEMM, f32 partial epilogue ---
// Same verified schedule as ffn_gemm256; blockIdx.z picks a KSUB-slice and a
// private f32 partial image Part[z] (plain stores; reduced by consumer).
template <int KFULL, int KSUB>
__global__ __launch_bounds__(512, 2) void gemm256sk(const bf16* __restrict__ A,
                                                    const bf16* __restrict__ Bt,
                                                    float* __restrict__ Part,
                                                    int N) {
  constexpr int NT = KSUB / 64;
  constexpr int NIT = NT / 2;
  __shared__ bf16 As[2 * 256 * 64];
  __shared__ bf16 Bs[3 * 256 * 64];
  const int tid = threadIdx.x;
  const int lane = tid & 63, wv = tid >> 6;
  const int wr = wv >> 2, wc = wv & 3;
  const int fr = lane & 15, quad = lane >> 4;
  const int swz = fr & 7;
  const int bm = blockIdx.y * 256;
  const int bn = blockIdx.x * 256;
  const int kbase = blockIdx.z * KSUB;
  const int lrow = tid >> 3;
  const int scol = ((tid & 7) ^ (lrow & 7)) * 8;
  const size_t rstep = (size_t)64 * KFULL;

  auto stageA = [&](int t, int half) {
    const int buf = (t & 1) * 16384;
    const bf16* g = A + (size_t)(bm + half * 128 + lrow) * KFULL + kbase + t * 64 + scol;
    bf16* d = As + buf + half * 8192 + (size_t)tid * 8;
    g2l16(d, g);
    g2l16(d + 4096, g + rstep);
  };
  auto stageB = [&](int t, int half, int buf) {
    const bf16* g = Bt + (size_t)(bn + half * 128 + lrow) * KFULL + kbase + t * 64 + scol;
    bf16* d = Bs + buf * 16384 + half * 8192 + (size_t)tid * 8;
    g2l16(d, g);
    g2l16(d + 4096, g + rstep);
  };

  f32x4 acc[8][4] = {};
  const int u0 = (quad ^ swz) * 8;

  stageA(0, 0); stageA(0, 1);
  stageB(0, 0, 0); stageB(0, 1, 0);
  stageB(1, 0, 1); stageB(1, 1, 1);
  asm volatile("s_waitcnt vmcnt(4)" ::: "memory");
  __builtin_amdgcn_s_barrier();

  int rb0 = 0, rb1 = 1, sb = 2;
  for (int it = 0; it < NIT; ++it) {
    const int t1 = 2 * it + 1;
#pragma unroll
    for (int j = 0; j < 8; ++j) {
      const int bufT = (j < 4) ? 0 : 16384;
      const int bufB = ((j < 4) ? rb0 : rb1) * 16384;
      const int qr4 = ((j & 3) >> 1) * 4, qc2 = ((j & 3) & 1) * 2;
      bf16x8 af[4][2], bv[2][2];
      const bf16* Ab = As + bufT + (size_t)(wr * 128 + fr) * 64;
      const bf16* Bb = Bs + bufB + (size_t)(wc * 64 + fr) * 64;
#pragma unroll
      for (int ii = 0; ii < 4; ++ii) {
        af[ii][0] = *reinterpret_cast<const bf16x8*>(Ab + (qr4 + ii) * 1024 + u0);
        af[ii][1] = *reinterpret_cast<const bf16x8*>(Ab + (qr4 + ii) * 1024 + (u0 ^ 32));
      }
#pragma unroll
      for (int jj = 0; jj < 2; ++jj) {
        bv[jj][0] = *reinterpret_cast<const bf16x8*>(Bb + (qc2 + jj) * 1024 + u0);
        bv[jj][1] = *reinterpret_cast<const bf16x8*>(Bb + (qc2 + jj) * 1024 + (u0 ^ 32));
      }
      if (j == 0)      stageA(t1, 0);
      else if (j == 1) stageA(t1, 1);
      else if (j == 2) { if (2 * it + 2 < NT) stageB(2 * it + 2, 0, sb); }
      else if (j == 3) { if (2 * it + 2 < NT) stageB(2 * it + 2, 1, sb); }
      else if (j == 4) { if (2 * it + 2 < NT) stageA(2 * it + 2, 0); }
      else if (j == 5) { if (2 * it + 2 < NT) stageA(2 * it + 2, 1); }
      else if (j == 6) { if (2 * it + 3 < NT) stageB(2 * it + 3, 0, rb0); }
      else             { if (2 * it + 3 < NT) stageB(2 * it + 3, 1, rb0); }
      __builtin_amdgcn_s_barrier();
      asm volatile("s_waitcnt lgkmcnt(0)" ::: "memory");
      __builtin_amdgcn_sched_barrier(0);
      __builtin_amdgcn_s_setprio(1);
#pragma unroll
      for (int ii = 0; ii < 4; ++ii)
#pragma unroll
        for (int jj = 0; jj < 2; ++jj) {
          acc[qr4 + ii][qc2 + jj] = __builtin_amdgcn_mfma_f32_16x16x32_bf16(
              af[ii][0], bv[jj][0], acc[qr4 + ii][qc2 + jj], 0, 0, 0);
          acc[qr4 + ii][qc2 + jj] = __builtin_amdgcn_mfma_f32_16x16x32_bf16(
              af[ii][1], bv[jj][1], acc[qr4 + ii][qc2 + jj], 0, 0, 0);
        }
      __builtin_amdgcn_s_setprio(0);
      if (j == 3) {
        if (2 * it + 2 < NT) asm volatile("s_waitcnt vmcnt(4)" ::: "memory");
        else                 asm volatile("s_waitcnt vmcnt(0)" ::: "memory");
      } else if (j == 7) {
        if (2 * it + 3 < NT)      asm volatile("s_waitcnt vmcnt(4)" ::: "memory");
        else if (2 * it + 2 < NT) asm volatile("s_waitcnt vmcnt(0)" ::: "memory");
      }
      __builtin_amdgcn_s_barrier();
    }
    const int nrb0 = sb; sb = rb1; rb1 = rb0; rb0 = nrb0;
  }

  float* P = Part + (size_t)blockIdx.z * ((size_t)Mr * N);
  const int er = quad * 4, ec = lane & 15;
#pragma unroll
  for (int i = 0; i < 8; ++i) {
    const int row = bm + wr * 128 + i * 16 + er;
#pragma unroll
    for (int jc = 0; jc < 4; ++jc) {
      const int col = bn + wc * 64 + jc * 16 + ec;
#pragma unroll
      for (int r = 0; r < 4; ++r)
        P[(size_t)(row + r) * N + col] = acc[i][jc][r];
    }
  }
}

// ------------------- repack: reduce 2 qkv partials + RoPE + Q/K/V split -----
// P (2 x f32 [M][3072] split-K partials) -> Qr[B,H,T,DH], Kr[B,HKV,T,DH]
// (RoPE'd), Vt[B,HKV,DH,T].  float2-vectorized partial reads (coalesced).
__global__ __launch_bounds__(256) void repack_k(const float* __restrict__ P,
                                                const float* __restrict__ cosb,
                                                const float* __restrict__ sinb,
                                                bf16* __restrict__ Qr,
                                                bf16* __restrict__ Kr,
                                                bf16* __restrict__ Vt) {
  constexpr size_t PS = (size_t)Mr * Nqkv;
  const int bt = blockIdx.x;
  const int b = bt >> 10, tp = bt & (Tc - 1);
  const int t0 = threadIdx.x;
  const float* r0 = P + (size_t)bt * Nqkv;
  const float* r1 = r0 + PS;
#pragma unroll
  for (int k = 0; k < 4; ++k) {      // Q: 1024 rope pairs
    int p2 = k * 256 + t0;
    int hh = p2 >> 6, i = p2 & 63;
    float c = cosb[tp * 64 + i], sn = sinb[tp * 64 + i];
    float2 v0 = *reinterpret_cast<const float2*>(r0 + hh * 128 + 2 * i);
    float2 v1 = *reinterpret_cast<const float2*>(r1 + hh * 128 + 2 * i);
    float x0 = v0.x + v1.x, x1 = v0.y + v1.y;
    bf16* dst = Qr + ((size_t)(b * Hc + hh) * Tc + tp) * DHc + 2 * i;
    dst[0] = f2b(x0 * c - x1 * sn);
    dst[1] = f2b(x0 * sn + x1 * c);
  }
  {                                   // K: 256 rope pairs
    int hh = t0 >> 6, i = t0 & 63;
    float c = cosb[tp * 64 + i], sn = sinb[tp * 64 + i];
    float2 v0 = *reinterpret_cast<const float2*>(r0 + 2048 + hh * 128 + 2 * i);
    float2 v1 = *reinterpret_cast<const float2*>(r1 + 2048 + hh * 128 + 2 * i);
    float x0 = v0.x + v1.x, x1 = v0.y + v1.y;
    bf16* dst = Kr + ((size_t)(b * HKVc + hh) * Tc + tp) * DHc + 2 * i;
    dst[0] = f2b(x0 * c - x1 * sn);
    dst[1] = f2b(x0 * sn + x1 * c);
  }
#pragma unroll
  for (int k = 0; k < 2; ++k) {      // V: 512 elems, transposed store
    int e = k * 256 + t0;
    int kvh = e >> 7, dd = e & 127;
    Vt[((size_t)(b * HKVc + kvh) * DHc + dd) * Tc + tp] = f2b(r0[2560 + e] + r1[2560 + e]);
  }
}

// ----------------------------------------------------- MFMA flash attention --
// block = (b, h, 64-row q-tile); 4 waves x 16 q-rows; 64-key tiles.
// (round-5 verified version: LDS-staged K/V — direct-global read regressed
//  78us in round 6: 16x64B scattered segments per frag vs 1KB coalesced here)
__global__ __launch_bounds__(256) void fattn(const bf16* __restrict__ Qr,
                                             const bf16* __restrict__ Kr,
                                             const bf16* __restrict__ Vt,
                                             bf16* __restrict__ ao) {
  __shared__ __align__(16) bf16 Ks[64 * 136];    // [key][d], +8 pad
  __shared__ __align__(16) bf16 Vts[128 * 72];   // [d][key], +8 pad
  __shared__ __align__(16) bf16 Ps[4][16 * 72];  // per-wave P
  const int idx = blockIdx.x;
  const int r = idx & 15;
  const int qt = (r & 1) ? (15 - (r >> 1)) : (r >> 1);  // pair-balanced
  const int h = (idx >> 4) & 15;
  const int b = idx >> 8;
  const int kv = h >> 2;
  const int t = threadIdx.x, lane = t & 63, wv = t >> 6;
  const int fr = lane & 15, quad = lane >> 4;

  const bf16* Qbase = Qr + ((size_t)(b * Hc + h) * Tc + qt * 64) * DHc;
  const bf16* Kbase = Kr + (size_t)(b * HKVc + kv) * Tc * DHc;
  const bf16* Vbase = Vt + (size_t)(b * HKVc + kv) * DHc * Tc;

  bf16x8 qf[4];
#pragma unroll
  for (int c = 0; c < 4; ++c)
    qf[c] = *reinterpret_cast<const bf16x8*>(Qbase + (size_t)(wv * 16 + fr) * DHc + c * 32 + quad * 8);

  float m[4], l[4];
  f32x4 o[8] = {};
#pragma unroll
  for (int r2 = 0; r2 < 4; ++r2) { m[r2] = -3.0e38f; l[r2] = 0.f; }

  for (int kt = 0; kt <= qt; ++kt) {
    __syncthreads();
    {  // stage K tile [64][128] -> Ks[64][136]
      const bf16* src = Kbase + (size_t)kt * 64 * DHc;
#pragma unroll
      for (int i2 = 0; i2 < 4; ++i2) {
        int flat = i2 * 256 + t;           // 16B units
        int row = flat >> 4, c16 = flat & 15;
        uint4 v = *reinterpret_cast<const uint4*>(src + (size_t)row * DHc + c16 * 8);
        *reinterpret_cast<uint4*>(&Ks[row * 136 + c16 * 8]) = v;
      }
      // stage V tile [128 d][64 key] -> Vts[128][72]
#pragma unroll
      for (int i2 = 0; i2 < 4; ++i2) {
        int flat = i2 * 256 + t;
        int row = flat >> 3, c8 = flat & 7;
        uint4 v = *reinterpret_cast<const uint4*>(Vbase + (size_t)row * Tc + kt * 64 + c8 * 8);
        *reinterpret_cast<uint4*>(&Vts[row * 72 + c8 * 8]) = v;
      }
    }
    __syncthreads();
    // S = Q K^T  (16 MFMA)
    f32x4 s[4];
#pragma unroll
    for (int cb = 0; cb < 4; ++cb) {
      f32x4 acc = {};
#pragma unroll
      for (int kc = 0; kc < 4; ++kc) {
        bf16x8 kf = *reinterpret_cast<const bf16x8*>(&Ks[(cb * 16 + fr) * 136 + kc * 32 + quad * 8]);
        acc = __builtin_amdgcn_mfma_f32_16x16x32_bf16(qf[kc], kf, acc, 0, 0, 0);
      }
      s[cb] = acc * 0.08838834764831845f;
    }
    if (kt == qt) {  // causal mask, diagonal tile only
#pragma unroll
      for (int cb = 0; cb < 4; ++cb)
#pragma unroll
        for (int r2 = 0; r2 < 4; ++r2) {
          int key = cb * 16 + fr;
          int qg = wv * 16 + quad * 4 + r2;
          if (key > qg) s[cb][r2] = -3.0e38f;
        }
    }
    // online softmax
    float tm[4], ts[4];
#pragma unroll
    for (int r2 = 0; r2 < 4; ++r2)
      tm[r2] = fmaxf(fmaxf(s[0][r2], s[1][r2]), fmaxf(s[2][r2], s[3][r2]));
#pragma unroll
    for (int off = 1; off < 16; off <<= 1)
#pragma unroll
      for (int r2 = 0; r2 < 4; ++r2)
        tm[r2] = fmaxf(tm[r2], __shfl_xor(tm[r2], off, 64));
    float al[4];
#pragma unroll
    for (int r2 = 0; r2 < 4; ++r2) {
      float mn = fmaxf(m[r2], tm[r2]);
      al[r2] = __expf(m[r2] - mn);
      m[r2] = mn;
      ts[r2] = 0.f;
    }
#pragma unroll
    for (int cb = 0; cb < 4; ++cb)
#pragma unroll
      for (int r2 = 0; r2 < 4; ++r2) {
        float e = __expf(s[cb][r2] - m[r2]);
        s[cb][r2] = e;
        ts[r2] += e;
      }
#pragma unroll
    for (int off = 1; off < 16; off <<= 1)
#pragma unroll
      for (int r2 = 0; r2 < 4; ++r2)
        ts[r2] += __shfl_xor(ts[r2], off, 64);
#pragma unroll
    for (int r2 = 0; r2 < 4; ++r2) l[r2] = l[r2] * al[r2] + ts[r2];
#pragma unroll
    for (int db = 0; db < 8; ++db)
#pragma unroll
      for (int r2 = 0; r2 < 4; ++r2) o[db][r2] *= al[r2];
    // P: C-layout regs -> LDS -> A-layout frags
    bf16* pw = Ps[wv];
#pragma unroll
    for (int cb = 0; cb < 4; ++cb)
#pragma unroll
      for (int r2 = 0; r2 < 4; ++r2)
        pw[(quad * 4 + r2) * 72 + cb * 16 + fr] = f2b(s[cb][r2]);
    bf16x8 pa[2];
    pa[0] = *reinterpret_cast<const bf16x8*>(&pw[fr * 72 + quad * 8]);
    pa[1] = *reinterpret_cast<const bf16x8*>(&pw[fr * 72 + 32 + quad * 8]);
    // O += P V  (16 MFMA)
#pragma unroll
    for (int db = 0; db < 8; ++db) {
      bf16x8 v0 = *reinterpret_cast<const bf16x8*>(&Vts[(db * 16 + fr) * 72 + quad * 8]);
      bf16x8 v1 = *reinterpret_cast<const bf16x8*>(&Vts[(db * 16 + fr) * 72 + 32 + quad * 8]);
      o[db] = __builtin_amdgcn_mfma_f32_16x16x32_bf16(pa[0], v0, o[db], 0, 0, 0);
      o[db] = __builtin_amdgcn_mfma_f32_16x16x32_bf16(pa[1], v1, o[db], 0, 0, 0);
    }
  }
#pragma unroll
  for (int r2 = 0; r2 < 4; ++r2) {
    float inv = 1.f / l[r2];
    int qg = qt * 64 + wv * 16 + quad * 4 + r2;
    bf16* orow = ao + (size_t)(b * Tc + qg) * Dc + h * DHc;
#pragma unroll
    for (int db = 0; db < 8; ++db)
      orow[db * 16 + fr] = f2b(o[db][r2] * inv);
  }
}

// ------------------------------------------------------------------ launch --
extern "C" void kernel_launch(void* const* d_in, const int* in_sizes, int n_in,
                              void* d_out, int out_size, void* d_ws, size_t ws_size,
                              hipStream_t stream) {
  const float* x    = (const float*)d_in[0];
  const float* fcos = (const float*)d_in[1];
  const float* fsin = (const float*)d_in[2];
  const float* wn1  = (const float*)d_in[3];
  const float* wn2  = (const float*)d_in[4];
  const float* wq   = (const float*)d_in[5];
  const float* wk   = (const float*)d_in[6];
  const float* wv   = (const float*)d_in[7];
  const float* wo   = (const float*)d_in[8];
  const float* w1   = (const float*)d_in[9];
  const float* w2   = (const float*)d_in[10];
  const float* w3   = (const float*)d_in[11];

  char* p = (char*)d_ws;
  bf16* wqkv_t = (bf16*)p;                 p += (size_t)Nqkv * Dc * 2;   // 12.58 MB
  float* xat   = (float*)d_ws;             // aliases wqkv_t (dead by wo-gemm)
  bf16* wo_t = (bf16*)p;                   p += (size_t)Dc * Dc * 2;     // 8.39 MB
  bf16* w13t = (bf16*)p;                   p += (size_t)2 * Fc * Dc * 2; // 46.14 MB
  bf16* w2t  = w13t;                       // aliases w13t (dead after ffn)
  bf16* xn   = (bf16*)p;                   p += (size_t)Mr * Dc * 2;     // 8.39 MB (reused as h)
  bf16* ao   = (bf16*)p;                   p += (size_t)Mr * Dc * 2;     // 8.39 MB
  bf16* act  = (bf16*)p;                   p += (size_t)Mr * Fc * 2;     // 23.07 MB
  float* Pbuf = (float*)p;                 p += (size_t)4 * Mr * Dc * 4; // 67.11 MB
  bf16* hb = xn;
  // Qr/Kr/Vt alias the act region (act written only after attention is done)
  bf16* Qr = act;                                        // 8.39 MB
  bf16* Kr = act + (size_t)Mr * Hc * DHc;                // 2.10 MB
  bf16* Vtb = Kr + (size_t)Mr * HKVc * DHc;              // 2.10 MB

  const dim3 blk(256);
  tcast_k<<<dim3(32, 32), blk, 0, stream>>>(wq, wqkv_t, 2048, 2048);
  tcast_k<<<dim3(8, 32), blk, 0, stream>>>(wk, wqkv_t + (size_t)2048 * 2048, 512, 2048);
  tcast_k<<<dim3(8, 32), blk, 0, stream>>>(wv, wqkv_t + (size_t)2560 * 2048, 512, 2048);
  tcast_k<<<dim3(32, 32), blk, 0, stream>>>(wo, wo_t, 2048, 2048);
  tcast_ffn<<<dim3(88, 32), blk, 0, stream>>>(w1, w13t, 0);
  tcast_ffn<<<dim3(88, 32), blk, 0, stream>>>(w3, w13t, 16);

  rmsnorm_k<<<Mr, blk, 0, stream>>>(x, wn1, xn);
  // qkv GEMM: partials = xn @ wqkv (split-K z=2, 8-phase); reduce fused in repack
  gemm256sk<Dc, 1024><<<dim3(Nqkv / 256, Mr / 256, 2), dim3(512), 0, stream>>>(xn, wqkv_t, Pbuf, Nqkv);
  repack_k<<<Mr, blk, 0, stream>>>(Pbuf, fcos, fsin, Qr, Kr, Vtb);
  fattn<<<Bc * Hc * 16, blk, 0, stream>>>(Qr, Kr, Vtb, ao);
  // wo GEMM: partials = ao @ wo (split-K, plain f32 stores)
  gemm256sk<Dc, 512><<<dim3(Dc / 256, Mr / 256, 4), dim3(512), 0, stream>>>(ao, wo_t, Pbuf, Dc);
  // fused: xat = x + sum(partials); hb = rmsnorm(xat) * wn2
  reduce4_rms<<<Mr, blk, 0, stream>>>(Pbuf, x, wn2, xat, hb);
  ffn_gemm256<Dc><<<dim3(2 * Fc / 256, Mr / 256), dim3(512), 0, stream>>>(hb, w13t, act);
  tcast_k<<<dim3(32, 88), blk, 0, stream>>>(w2, w2t, 2048, 5632);
  // w2 GEMM: partials = act @ w2 (split-K); d_out = xat + sum(partials)
  gemm256sk<Fc, 1408><<<dim3(Dc / 256, Mr / 256, 4), dim3(512), 0, stream>>>(act, w2t, Pbuf, Dc);
  reduce4_add<<<Mr * Dc / 1024, blk, 0, stream>>>(Pbuf, xat, (float*)d_out);
}

// Round 8
// 560.967 us; speedup vs baseline: 1.1589x; 1.0060x over previous
//
#include <hip/hip_runtime.h>
#include <hip/hip_bf16.h>
#include <math.h>

typedef __hip_bfloat16 bf16;
typedef __attribute__((ext_vector_type(8))) short bf16x8;   // 8 bf16 = 4 VGPR
typedef __attribute__((ext_vector_type(4))) float f32x4;

__device__ __forceinline__ float b2f(bf16 v) { return __bfloat162float(v); }
__device__ __forceinline__ bf16  f2b(float v) { return __float2bfloat16(v); }

constexpr int Bc = 2, Tc = 1024, Dc = 2048, Hc = 16, HKVc = 4, DHc = 128, Fc = 5632;
constexpr int Mr = Bc * Tc;                      // 2048 rows
constexpr int Nqkv = Hc * DHc + 2 * HKVc * DHc;  // 3072

// async 16B global->LDS (lands at wave-uniform base + lane*16)
__device__ __forceinline__ void g2l16(void* lds, const void* g) {
  __builtin_amdgcn_global_load_lds(
      (const __attribute__((address_space(1))) unsigned int*)g,
      (__attribute__((address_space(3))) unsigned int*)lds, 16, 0, 0);
}

// ------------------------------------------------------- transpose + cast ---
// src fp32 [K][N] row-major  ->  dst bf16 [N][K] row-major (B^T for MFMA GEMM)
__global__ __launch_bounds__(256) void tcast_k(const float* __restrict__ src,
                                               bf16* __restrict__ dst,
                                               int N, int K) {
  __shared__ bf16 tile[64][68];
  const int t = threadIdx.x;
  const int n0 = blockIdx.x * 64, k0 = blockIdx.y * 64;
#pragma unroll
  for (int it = 0; it < 4; ++it) {
    const int kl = it * 16 + (t >> 4);
    const int nl = (t & 15) * 4;
    float4 v = *reinterpret_cast<const float4*>(src + (size_t)(k0 + kl) * N + n0 + nl);
    tile[kl][nl]     = f2b(v.x);
    tile[kl][nl + 1] = f2b(v.y);
    tile[kl][nl + 2] = f2b(v.z);
    tile[kl][nl + 3] = f2b(v.w);
  }
  __syncthreads();
  union { uint4 u; bf16 h[8]; } o;   // 16 B
#pragma unroll
  for (int it = 0; it < 2; ++it) {
    const int nl = it * 32 + (t >> 3);
    const int kl = (t & 7) * 8;
#pragma unroll
    for (int j = 0; j < 8; ++j) o.h[j] = tile[kl + j][nl];
    *reinterpret_cast<uint4*>(dst + (size_t)(n0 + nl) * K + k0 + kl) = o.u;
  }
}

// --------------------- transpose + cast + 16-row gate/up interleave (FFN) ---
// src fp32 [2048][5632] -> w13t rows: col n of w1 -> row 32*(n>>4)+(n&15);
// col n of w3 -> +16.  (so each 256-row B-tile pairs gate/up per 16-block)
__global__ __launch_bounds__(256) void tcast_ffn(const float* __restrict__ src,
                                                 bf16* __restrict__ dst,
                                                 int off) {
  __shared__ bf16 tile[64][68];
  const int t = threadIdx.x;
  const int n0 = blockIdx.x * 64, k0 = blockIdx.y * 64;
#pragma unroll
  for (int it = 0; it < 4; ++it) {
    const int kl = it * 16 + (t >> 4);
    const int nl = (t & 15) * 4;
    float4 v = *reinterpret_cast<const float4*>(src + (size_t)(k0 + kl) * Fc + n0 + nl);
    tile[kl][nl]     = f2b(v.x);
    tile[kl][nl + 1] = f2b(v.y);
    tile[kl][nl + 2] = f2b(v.z);
    tile[kl][nl + 3] = f2b(v.w);
  }
  __syncthreads();
  union { uint4 u; bf16 h[8]; } o;   // 16 B
#pragma unroll
  for (int it = 0; it < 2; ++it) {
    const int nl = it * 32 + (t >> 3);
    const int kl = (t & 7) * 8;
#pragma unroll
    for (int j = 0; j < 8; ++j) o.h[j] = tile[kl + j][nl];
    const int n = n0 + nl;
    const int r = ((n >> 4) << 5) + (n & 15) + off;
    *reinterpret_cast<uint4*>(dst + (size_t)r * Dc + k0 + kl) = o.u;
  }
}

// ---------------------------------------------------------------- RMSNorm ---
__global__ __launch_bounds__(256) void rmsnorm_k(const float* __restrict__ x,
                                                 const float* __restrict__ w,
                                                 bf16* __restrict__ out) {
  const size_t rbase = (size_t)blockIdx.x * Dc;
  float ss = 0.f;
  for (int i = threadIdx.x; i < Dc; i += 256) {
    float v = x[rbase + i];
    ss += v * v;
  }
#pragma unroll
  for (int off = 32; off > 0; off >>= 1) ss += __shfl_down(ss, off, 64);
  __shared__ float red[4];
  const int lane = threadIdx.x & 63, wid = threadIdx.x >> 6;
  if (lane == 0) red[wid] = ss;
  __syncthreads();
  const float scale = rsqrtf((red[0] + red[1] + red[2] + red[3]) / (float)Dc + 1e-6f);
  for (int i = threadIdx.x; i < Dc; i += 256)
    out[rbase + i] = f2b(x[rbase + i] * scale * w[i]);
}

// ----------------- reduce 4 split-K partials + residual + RMSNorm (fused) ---
// xat = x + sum_z P[z];  hb = rmsnorm(xat) * w   (one pass, one block/row)
__global__ __launch_bounds__(256) void reduce4_rms(const float* __restrict__ P,
                                                   const float* __restrict__ x,
                                                   const float* __restrict__ w,
                                                   float* __restrict__ xat,
                                                   bf16* __restrict__ hb) {
  constexpr size_t PS = (size_t)Mr * Dc;
  const size_t base4 = (size_t)blockIdx.x * (Dc / 4);
  const int t = threadIdx.x;
  float4 v[2];
  float ss = 0.f;
#pragma unroll
  for (int j = 0; j < 2; ++j) {
    const size_t c4 = base4 + t + j * 256;
    float4 a = reinterpret_cast<const float4*>(x)[c4];
#pragma unroll
    for (int z = 0; z < 4; ++z) {
      float4 q = reinterpret_cast<const float4*>(P + z * PS)[c4];
      a.x += q.x; a.y += q.y; a.z += q.z; a.w += q.w;
    }
    reinterpret_cast<float4*>(xat)[c4] = a;
    ss += a.x * a.x + a.y * a.y + a.z * a.z + a.w * a.w;
    v[j] = a;
  }
#pragma unroll
  for (int off = 32; off > 0; off >>= 1) ss += __shfl_down(ss, off, 64);
  __shared__ float red[4];
  const int lane = t & 63, wid = t >> 6;
  if (lane == 0) red[wid] = ss;
  __syncthreads();
  const float scale = rsqrtf((red[0] + red[1] + red[2] + red[3]) / (float)Dc + 1e-6f);
  bf16* hrow = hb + (size_t)blockIdx.x * Dc;
#pragma unroll
  for (int j = 0; j < 2; ++j) {
    const int c = (t + j * 256) * 4;
    hrow[c]     = f2b(v[j].x * scale * w[c]);
    hrow[c + 1] = f2b(v[j].y * scale * w[c + 1]);
    hrow[c + 2] = f2b(v[j].z * scale * w[c + 2]);
    hrow[c + 3] = f2b(v[j].w * scale * w[c + 3]);
  }
}

// --------------------- reduce 4 split-K partials + residual (final output) --
__global__ __launch_bounds__(256) void reduce4_add(const float* __restrict__ P,
                                                   const float* __restrict__ res,
                                                   float* __restrict__ out) {
  constexpr size_t PS = (size_t)Mr * Dc;
  const size_t c4 = (size_t)blockIdx.x * 256 + threadIdx.x;
  float4 a = reinterpret_cast<const float4*>(res)[c4];
#pragma unroll
  for (int z = 0; z < 4; ++z) {
    float4 q = reinterpret_cast<const float4*>(P + z * PS)[c4];
    a.x += q.x; a.y += q.y; a.z += q.z; a.w += q.w;
  }
  reinterpret_cast<float4*>(out)[c4] = a;
}

// -------------------------- FFN 256x256 8-phase MFMA GEMM (T2+T3+T4+T5) ----
// 512 thr (8 waves, 2Mx4N), BK=64. A dbuf 2x32KB, B tribuf 3x32KB = 160KB LDS.
// Staging map (race-free): ph0-1 A(t+1); ph2-3 B(t+2); ph4-5 A(t+2);
// ph6-7 B(t+3). vmcnt(4) at ph3/ph7 (2 half-tiles slack). XOR-swizzle:
// pre-swizzled global src col + swizzled ds_read (involution, #21).
// B rows = w13t 16-interleaved gate/up -> silu pairs are lane-local.
template <int K>
__global__ __launch_bounds__(512, 2) void ffn_gemm256(const bf16* __restrict__ A,
                                                      const bf16* __restrict__ B,
                                                      bf16* __restrict__ act) {
  constexpr int NT = K / 64;     // K-tiles
  constexpr int NIT = NT / 2;    // 2 tiles per iteration
  __shared__ bf16 As[2 * 256 * 64];
  __shared__ bf16 Bs[3 * 256 * 64];
  const int tid = threadIdx.x;
  const int lane = tid & 63, wv = tid >> 6;
  const int wr = wv >> 2, wc = wv & 3;
  const int fr = lane & 15, quad = lane >> 4;
  const int swz = fr & 7;
  const int bm = blockIdx.y * 256;
  const int bn = blockIdx.x * 256;  // w13t row base (128 output cols)
  // staging coords: thread covers 2x 16B chunks of a 128x64 half-tile
  const int lrow = tid >> 3;                          // 0..63
  const int scol = ((tid & 7) ^ (lrow & 7)) * 8;      // pre-swizzled src col
  const size_t rstep = (size_t)64 * K;

  auto stageA = [&](int t, int half) {
    const int buf = (t & 1) * 16384;
    const bf16* g = A + (size_t)(bm + half * 128 + lrow) * K + t * 64 + scol;
    bf16* d = As + buf + half * 8192 + (size_t)tid * 8;
    g2l16(d, g);
    g2l16(d + 4096, g + rstep);
  };
  auto stageB = [&](int t, int half, int buf) {
    const bf16* g = B + (size_t)(bn + half * 128 + lrow) * K + t * 64 + scol;
    bf16* d = Bs + buf * 16384 + half * 8192 + (size_t)tid * 8;
    g2l16(d, g);
    g2l16(d + 4096, g + rstep);
  };

  f32x4 acc[8][4] = {};
  const int u0 = (quad ^ swz) * 8;   // ksub 0 col offset (elems); ksub1 = ^32

  // prologue: A(0), B(0)->buf0, B(1)->buf1; wait all but B(1)
  stageA(0, 0); stageA(0, 1);
  stageB(0, 0, 0); stageB(0, 1, 0);
  stageB(1, 0, 1); stageB(1, 1, 1);
  asm volatile("s_waitcnt vmcnt(4)" ::: "memory");
  __builtin_amdgcn_s_barrier();

  int rb0 = 0, rb1 = 1, sb = 2;
  for (int it = 0; it < NIT; ++it) {
    const int t1 = 2 * it + 1;
#pragma unroll
    for (int j = 0; j < 8; ++j) {
      const int bufT = (j < 4) ? 0 : 16384;
      const int bufB = ((j < 4) ? rb0 : rb1) * 16384;
      const int qr4 = ((j & 3) >> 1) * 4, qc2 = ((j & 3) & 1) * 2;
      // ---- ds-read frags for this quadrant (12 x ds_read_b128, swizzled)
      bf16x8 af[4][2], bv[2][2];
      const bf16* Ab = As + bufT + (size_t)(wr * 128 + fr) * 64;
      const bf16* Bb = Bs + bufB + (size_t)(wc * 64 + fr) * 64;
#pragma unroll
      for (int ii = 0; ii < 4; ++ii) {
        af[ii][0] = *reinterpret_cast<const bf16x8*>(Ab + (qr4 + ii) * 1024 + u0);
        af[ii][1] = *reinterpret_cast<const bf16x8*>(Ab + (qr4 + ii) * 1024 + (u0 ^ 32));
      }
#pragma unroll
      for (int jj = 0; jj < 2; ++jj) {
        bv[jj][0] = *reinterpret_cast<const bf16x8*>(Bb + (qc2 + jj) * 1024 + u0);
        bv[jj][1] = *reinterpret_cast<const bf16x8*>(Bb + (qc2 + jj) * 1024 + (u0 ^ 32));
      }
      // ---- stage one half-tile (2 x global_load_lds)
      if (j == 0)      stageA(t1, 0);
      else if (j == 1) stageA(t1, 1);
      else if (j == 2) { if (2 * it + 2 < NT) stageB(2 * it + 2, 0, sb); }
      else if (j == 3) { if (2 * it + 2 < NT) stageB(2 * it + 2, 1, sb); }
      else if (j == 4) { if (2 * it + 2 < NT) stageA(2 * it + 2, 0); }
      else if (j == 5) { if (2 * it + 2 < NT) stageA(2 * it + 2, 1); }
      else if (j == 6) { if (2 * it + 3 < NT) stageB(2 * it + 3, 0, rb0); }
      else             { if (2 * it + 3 < NT) stageB(2 * it + 3, 1, rb0); }
      __builtin_amdgcn_s_barrier();
      asm volatile("s_waitcnt lgkmcnt(0)" ::: "memory");
      __builtin_amdgcn_sched_barrier(0);
      __builtin_amdgcn_s_setprio(1);
#pragma unroll
      for (int ii = 0; ii < 4; ++ii)
#pragma unroll
        for (int jj = 0; jj < 2; ++jj) {
          acc[qr4 + ii][qc2 + jj] = __builtin_amdgcn_mfma_f32_16x16x32_bf16(
              af[ii][0], bv[jj][0], acc[qr4 + ii][qc2 + jj], 0, 0, 0);
          acc[qr4 + ii][qc2 + jj] = __builtin_amdgcn_mfma_f32_16x16x32_bf16(
              af[ii][1], bv[jj][1], acc[qr4 + ii][qc2 + jj], 0, 0, 0);
        }
      __builtin_amdgcn_s_setprio(0);
      if (j == 3) {
        if (2 * it + 2 < NT) asm volatile("s_waitcnt vmcnt(4)" ::: "memory");
        else                 asm volatile("s_waitcnt vmcnt(0)" ::: "memory");
      } else if (j == 7) {
        if (2 * it + 3 < NT)      asm volatile("s_waitcnt vmcnt(4)" ::: "memory");
        else if (2 * it + 2 < NT) asm volatile("s_waitcnt vmcnt(0)" ::: "memory");
      }
      __builtin_amdgcn_s_barrier();
    }
    const int nrb0 = sb; sb = rb1; rb1 = rb0; rb0 = nrb0;
  }

  // ---- epilogue: silu(gate)*up, pairs are lane-local (j even=gate, odd=up)
  const int er = quad * 4, ec = lane & 15;
#pragma unroll
  for (int i = 0; i < 8; ++i) {
    const int row = bm + wr * 128 + i * 16 + er;
#pragma unroll
    for (int jp = 0; jp < 2; ++jp) {
      const f32x4 g = acc[i][2 * jp], u = acc[i][2 * jp + 1];
      const int f = blockIdx.x * 128 + wc * 32 + jp * 16 + ec;
#pragma unroll
      for (int r = 0; r < 4; ++r) {
        const float sg = g[r] / (1.f + __expf(-g[r]));
        act[(size_t)(row + r) * Fc + f] = f2b(sg * u[r]);
      }
    }
  }
}

// --------------- split-K 256x256 8-phase MFMA GEMM, f32 partial epilogue ---
// Same verified schedule as ffn_gemm256; blockIdx.z picks a KSUB-slice and a
// private f32 partial image Part[z] (plain stores; reduced by consumer).
template <int KFULL, int KSUB>
__global__ __launch_bounds__(512, 2) void gemm256sk(const bf16* __restrict__ A,
                                                    const bf16* __restrict__ Bt,
                                                    float* __restrict__ Part,
                                                    int N) {
  constexpr int NT = KSUB / 64;
  constexpr int NIT = NT / 2;
  __shared__ bf16 As[2 * 256 * 64];
  __shared__ bf16 Bs[3 * 256 * 64];
  const int tid = threadIdx.x;
  const int lane = tid & 63, wv = tid >> 6;
  const int wr = wv >> 2, wc = wv & 3;
  const int fr = lane & 15, quad = lane >> 4;
  const int swz = fr & 7;
  const int bm = blockIdx.y * 256;
  const int bn = blockIdx.x * 256;
  const int kbase = blockIdx.z * KSUB;
  const int lrow = tid >> 3;
  const int scol = ((tid & 7) ^ (lrow & 7)) * 8;
  const size_t rstep = (size_t)64 * KFULL;

  auto stageA = [&](int t, int half) {
    const int buf = (t & 1) * 16384;
    const bf16* g = A + (size_t)(bm + half * 128 + lrow) * KFULL + kbase + t * 64 + scol;
    bf16* d = As + buf + half * 8192 + (size_t)tid * 8;
    g2l16(d, g);
    g2l16(d + 4096, g + rstep);
  };
  auto stageB = [&](int t, int half, int buf) {
    const bf16* g = Bt + (size_t)(bn + half * 128 + lrow) * KFULL + kbase + t * 64 + scol;
    bf16* d = Bs + buf * 16384 + half * 8192 + (size_t)tid * 8;
    g2l16(d, g);
    g2l16(d + 4096, g + rstep);
  };

  f32x4 acc[8][4] = {};
  const int u0 = (quad ^ swz) * 8;

  stageA(0, 0); stageA(0, 1);
  stageB(0, 0, 0); stageB(0, 1, 0);
  stageB(1, 0, 1); stageB(1, 1, 1);
  asm volatile("s_waitcnt vmcnt(4)" ::: "memory");
  __builtin_amdgcn_s_barrier();

  int rb0 = 0, rb1 = 1, sb = 2;
  for (int it = 0; it < NIT; ++it) {
    const int t1 = 2 * it + 1;
#pragma unroll
    for (int j = 0; j < 8; ++j) {
      const int bufT = (j < 4) ? 0 : 16384;
      const int bufB = ((j < 4) ? rb0 : rb1) * 16384;
      const int qr4 = ((j & 3) >> 1) * 4, qc2 = ((j & 3) & 1) * 2;
      bf16x8 af[4][2], bv[2][2];
      const bf16* Ab = As + bufT + (size_t)(wr * 128 + fr) * 64;
      const bf16* Bb = Bs + bufB + (size_t)(wc * 64 + fr) * 64;
#pragma unroll
      for (int ii = 0; ii < 4; ++ii) {
        af[ii][0] = *reinterpret_cast<const bf16x8*>(Ab + (qr4 + ii) * 1024 + u0);
        af[ii][1] = *reinterpret_cast<const bf16x8*>(Ab + (qr4 + ii) * 1024 + (u0 ^ 32));
      }
#pragma unroll
      for (int jj = 0; jj < 2; ++jj) {
        bv[jj][0] = *reinterpret_cast<const bf16x8*>(Bb + (qc2 + jj) * 1024 + u0);
        bv[jj][1] = *reinterpret_cast<const bf16x8*>(Bb + (qc2 + jj) * 1024 + (u0 ^ 32));
      }
      if (j == 0)      stageA(t1, 0);
      else if (j == 1) stageA(t1, 1);
      else if (j == 2) { if (2 * it + 2 < NT) stageB(2 * it + 2, 0, sb); }
      else if (j == 3) { if (2 * it + 2 < NT) stageB(2 * it + 2, 1, sb); }
      else if (j == 4) { if (2 * it + 2 < NT) stageA(2 * it + 2, 0); }
      else if (j == 5) { if (2 * it + 2 < NT) stageA(2 * it + 2, 1); }
      else if (j == 6) { if (2 * it + 3 < NT) stageB(2 * it + 3, 0, rb0); }
      else             { if (2 * it + 3 < NT) stageB(2 * it + 3, 1, rb0); }
      __builtin_amdgcn_s_barrier();
      asm volatile("s_waitcnt lgkmcnt(0)" ::: "memory");
      __builtin_amdgcn_sched_barrier(0);
      __builtin_amdgcn_s_setprio(1);
#pragma unroll
      for (int ii = 0; ii < 4; ++ii)
#pragma unroll
        for (int jj = 0; jj < 2; ++jj) {
          acc[qr4 + ii][qc2 + jj] = __builtin_amdgcn_mfma_f32_16x16x32_bf16(
              af[ii][0], bv[jj][0], acc[qr4 + ii][qc2 + jj], 0, 0, 0);
          acc[qr4 + ii][qc2 + jj] = __builtin_amdgcn_mfma_f32_16x16x32_bf16(
              af[ii][1], bv[jj][1], acc[qr4 + ii][qc2 + jj], 0, 0, 0);
        }
      __builtin_amdgcn_s_setprio(0);
      if (j == 3) {
        if (2 * it + 2 < NT) asm volatile("s_waitcnt vmcnt(4)" ::: "memory");
        else                 asm volatile("s_waitcnt vmcnt(0)" ::: "memory");
      } else if (j == 7) {
        if (2 * it + 3 < NT)      asm volatile("s_waitcnt vmcnt(4)" ::: "memory");
        else if (2 * it + 2 < NT) asm volatile("s_waitcnt vmcnt(0)" ::: "memory");
      }
      __builtin_amdgcn_s_barrier();
    }
    const int nrb0 = sb; sb = rb1; rb1 = rb0; rb0 = nrb0;
  }

  float* P = Part + (size_t)blockIdx.z * ((size_t)Mr * N);
  const int er = quad * 4, ec = lane & 15;
#pragma unroll
  for (int i = 0; i < 8; ++i) {
    const int row = bm + wr * 128 + i * 16 + er;
#pragma unroll
    for (int jc = 0; jc < 4; ++jc) {
      const int col = bn + wc * 64 + jc * 16 + ec;
#pragma unroll
      for (int r = 0; r < 4; ++r)
        P[(size_t)(row + r) * N + col] = acc[i][jc][r];
    }
  }
}

// ------------------- repack: reduce 2 qkv partials + RoPE + Q/K/V split -----
// P (2 x f32 [M][3072] split-K partials) -> Qr[B,H,T,DH], Kr[B,HKV,T,DH]
// (RoPE'd), Vt[B,HKV,DH,T].  float2-vectorized partial reads (coalesced).
__global__ __launch_bounds__(256) void repack_k(const float* __restrict__ P,
                                                const float* __restrict__ cosb,
                                                const float* __restrict__ sinb,
                                                bf16* __restrict__ Qr,
                                                bf16* __restrict__ Kr,
                                                bf16* __restrict__ Vt) {
  constexpr size_t PS = (size_t)Mr * Nqkv;
  const int bt = blockIdx.x;
  const int b = bt >> 10, tp = bt & (Tc - 1);
  const int t0 = threadIdx.x;
  const float* r0 = P + (size_t)bt * Nqkv;
  const float* r1 = r0 + PS;
#pragma unroll
  for (int k = 0; k < 4; ++k) {      // Q: 1024 rope pairs
    int p2 = k * 256 + t0;
    int hh = p2 >> 6, i = p2 & 63;
    float c = cosb[tp * 64 + i], sn = sinb[tp * 64 + i];
    float2 v0 = *reinterpret_cast<const float2*>(r0 + hh * 128 + 2 * i);
    float2 v1 = *reinterpret_cast<const float2*>(r1 + hh * 128 + 2 * i);
    float x0 = v0.x + v1.x, x1 = v0.y + v1.y;
    bf16* dst = Qr + ((size_t)(b * Hc + hh) * Tc + tp) * DHc + 2 * i;
    dst[0] = f2b(x0 * c - x1 * sn);
    dst[1] = f2b(x0 * sn + x1 * c);
  }
  {                                   // K: 256 rope pairs
    int hh = t0 >> 6, i = t0 & 63;
    float c = cosb[tp * 64 + i], sn = sinb[tp * 64 + i];
    float2 v0 = *reinterpret_cast<const float2*>(r0 + 2048 + hh * 128 + 2 * i);
    float2 v1 = *reinterpret_cast<const float2*>(r1 + 2048 + hh * 128 + 2 * i);
    float x0 = v0.x + v1.x, x1 = v0.y + v1.y;
    bf16* dst = Kr + ((size_t)(b * HKVc + hh) * Tc + tp) * DHc + 2 * i;
    dst[0] = f2b(x0 * c - x1 * sn);
    dst[1] = f2b(x0 * sn + x1 * c);
  }
#pragma unroll
  for (int k = 0; k < 2; ++k) {      // V: 512 elems, transposed store
    int e = k * 256 + t0;
    int kvh = e >> 7, dd = e & 127;
    Vt[((size_t)(b * HKVc + kvh) * DHc + dd) * Tc + tp] = f2b(r0[2560 + e] + r1[2560 + e]);
  }
}

// ----------------------------------------------------- MFMA flash attention --
// block = (b, h, 64-row q-tile); 4 waves x 16 q-rows; 64-key tiles.
// Async double-buffered K/V staging via global_load_lds (stage t+1 during
// compute t); ONE barrier/tile (its implicit vmcnt(0) drain = the wait).
// Linear LDS dest (g2l16 requirement) + #21 both-sides XOR swizzle:
// source chunk c ^= row&7 at stage, same XOR on ds_read -> b128 bank floor.
// LDS 73KB -> 2 blocks/CU; all 512 blocks co-resident.
__global__ __launch_bounds__(256) void fattn(const bf16* __restrict__ Qr,
                                             const bf16* __restrict__ Kr,
                                             const bf16* __restrict__ Vt,
                                             bf16* __restrict__ ao) {
  __shared__ __align__(16) bf16 Ks[2][64 * 128];   // [key][d], linear, swz
  __shared__ __align__(16) bf16 Vts[2][128 * 64];  // [d][key], linear, swz
  __shared__ __align__(16) bf16 Ps[4][16 * 72];    // per-wave P
  const int idx = blockIdx.x;
  const int r = idx & 15;
  const int qt = (r & 1) ? (15 - (r >> 1)) : (r >> 1);  // pair-balanced
  const int h = (idx >> 4) & 15;
  const int b = idx >> 8;
  const int kv = h >> 2;
  const int t = threadIdx.x, lane = t & 63, wv = t >> 6;
  const int fr = lane & 15, quad = lane >> 4;

  const bf16* Qbase = Qr + ((size_t)(b * Hc + h) * Tc + qt * 64) * DHc;
  const bf16* Kbase = Kr + (size_t)(b * HKVc + kv) * Tc * DHc;
  const bf16* Vbase = Vt + (size_t)(b * HKVc + kv) * DHc * Tc;

  // stage K tile [64 key][128 d]: 4 rounds x 256thr x 16B; src col swizzled
  auto stageK = [&](int kt, int buf) {
    const bf16* src = Kbase + (size_t)kt * 64 * DHc;
#pragma unroll
    for (int rr = 0; rr < 4; ++rr) {
      const int row = rr * 16 + (t >> 4);
      const int cS = (t & 15) ^ (row & 7);
      g2l16(&Ks[buf][rr * 2048 + t * 8], src + row * DHc + cS * 8);
    }
  };
  // stage V tile [128 d][64 key]: 4 rounds; src chunk swizzled (8 chunks/row)
  auto stageV = [&](int kt, int buf) {
#pragma unroll
    for (int rr = 0; rr < 4; ++rr) {
      const int row = rr * 32 + (t >> 3);
      const int cS = (t & 7) ^ (row & 7);
      g2l16(&Vts[buf][rr * 2048 + t * 8], Vbase + (size_t)row * Tc + kt * 64 + cS * 8);
    }
  };

  bf16x8 qf[4];
#pragma unroll
  for (int c = 0; c < 4; ++c)
    qf[c] = *reinterpret_cast<const bf16x8*>(Qbase + (size_t)(wv * 16 + fr) * DHc + c * 32 + quad * 8);

  float m[4], l[4];
  f32x4 o[8] = {};
#pragma unroll
  for (int r2 = 0; r2 < 4; ++r2) { m[r2] = -3.0e38f; l[r2] = 0.f; }

  stageK(0, 0);
  stageV(0, 0);
  __syncthreads();          // drains vmcnt -> tile 0 ready
  int buf = 0;

  for (int kt = 0; kt <= qt; ++kt) {
    if (kt < qt) { stageK(kt + 1, buf ^ 1); stageV(kt + 1, buf ^ 1); }  // async
    const int sw = fr & 7;
    // S = Q K^T  (16 MFMA, swizzled ds_read)
    f32x4 s[4];
    __builtin_amdgcn_s_setprio(1);
#pragma unroll
    for (int cb = 0; cb < 4; ++cb) {
      f32x4 acc = {};
#pragma unroll
      for (int kc = 0; kc < 4; ++kc) {
        bf16x8 kf = *reinterpret_cast<const bf16x8*>(
            &Ks[buf][(cb * 16 + fr) * 128 + (((kc << 2) + quad) ^ sw) * 8]);
        acc = __builtin_amdgcn_mfma_f32_16x16x32_bf16(qf[kc], kf, acc, 0, 0, 0);
      }
      s[cb] = acc * 0.08838834764831845f;
    }
    __builtin_amdgcn_s_setprio(0);
    if (kt == qt) {  // causal mask, diagonal tile only
#pragma unroll
      for (int cb = 0; cb < 4; ++cb)
#pragma unroll
        for (int r2 = 0; r2 < 4; ++r2) {
          int key = cb * 16 + fr;
          int qg = wv * 16 + quad * 4 + r2;
          if (key > qg) s[cb][r2] = -3.0e38f;
        }
    }
    // online softmax
    float tm[4], ts[4];
#pragma unroll
    for (int r2 = 0; r2 < 4; ++r2)
      tm[r2] = fmaxf(fmaxf(s[0][r2], s[1][r2]), fmaxf(s[2][r2], s[3][r2]));
#pragma unroll
    for (int off = 1; off < 16; off <<= 1)
#pragma unroll
      for (int r2 = 0; r2 < 4; ++r2)
        tm[r2] = fmaxf(tm[r2], __shfl_xor(tm[r2], off, 64));
    float al[4];
#pragma unroll
    for (int r2 = 0; r2 < 4; ++r2) {
      float mn = fmaxf(m[r2], tm[r2]);
      al[r2] = __expf(m[r2] - mn);
      m[r2] = mn;
      ts[r2] = 0.f;
    }
#pragma unroll
    for (int cb = 0; cb < 4; ++cb)
#pragma unroll
      for (int r2 = 0; r2 < 4; ++r2) {
        float e = __expf(s[cb][r2] - m[r2]);
        s[cb][r2] = e;
        ts[r2] += e;
      }
#pragma unroll
    for (int off = 1; off < 16; off <<= 1)
#pragma unroll
      for (int r2 = 0; r2 < 4; ++r2)
        ts[r2] += __shfl_xor(ts[r2], off, 64);
#pragma unroll
    for (int r2 = 0; r2 < 4; ++r2) l[r2] = l[r2] * al[r2] + ts[r2];
#pragma unroll
    for (int db = 0; db < 8; ++db)
#pragma unroll
      for (int r2 = 0; r2 < 4; ++r2) o[db][r2] *= al[r2];
    // P: C-layout regs -> per-wave LDS -> A-layout frags
    bf16* pw = Ps[wv];
#pragma unroll
    for (int cb = 0; cb < 4; ++cb)
#pragma unroll
      for (int r2 = 0; r2 < 4; ++r2)
        pw[(quad * 4 + r2) * 72 + cb * 16 + fr] = f2b(s[cb][r2]);
    bf16x8 pa[2];
    pa[0] = *reinterpret_cast<const bf16x8*>(&pw[fr * 72 + quad * 8]);
    pa[1] = *reinterpret_cast<const bf16x8*>(&pw[fr * 72 + 32 + quad * 8]);
    // O += P V  (16 MFMA, swizzled ds_read)
    __builtin_amdgcn_s_setprio(1);
#pragma unroll
    for (int db = 0; db < 8; ++db) {
      bf16x8 v0 = *reinterpret_cast<const bf16x8*>(
          &Vts[buf][(db * 16 + fr) * 64 + (quad ^ sw) * 8]);
      bf16x8 v1 = *reinterpret_cast<const bf16x8*>(
          &Vts[buf][(db * 16 + fr) * 64 + ((4 + quad) ^ sw) * 8]);
      o[db] = __builtin_amdgcn_mfma_f32_16x16x32_bf16(pa[0], v0, o[db], 0, 0, 0);
      o[db] = __builtin_amdgcn_mfma_f32_16x16x32_bf16(pa[1], v1, o[db], 0, 0, 0);
    }
    __builtin_amdgcn_s_setprio(0);
    __syncthreads();        // drains next-tile staging + syncs buf reuse
    buf ^= 1;
  }
#pragma unroll
  for (int r2 = 0; r2 < 4; ++r2) {
    float inv = 1.f / l[r2];
    int qg = qt * 64 + wv * 16 + quad * 4 + r2;
    bf16* orow = ao + (size_t)(b * Tc + qg) * Dc + h * DHc;
#pragma unroll
    for (int db = 0; db < 8; ++db)
      orow[db * 16 + fr] = f2b(o[db][r2] * inv);
  }
}

// ------------------------------------------------------------------ launch --
extern "C" void kernel_launch(void* const* d_in, const int* in_sizes, int n_in,
                              void* d_out, int out_size, void* d_ws, size_t ws_size,
                              hipStream_t stream) {
  const float* x    = (const float*)d_in[0];
  const float* fcos = (const float*)d_in[1];
  const float* fsin = (const float*)d_in[2];
  const float* wn1  = (const float*)d_in[3];
  const float* wn2  = (const float*)d_in[4];
  const float* wq   = (const float*)d_in[5];
  const float* wk   = (const float*)d_in[6];
  const float* wv   = (const float*)d_in[7];
  const float* wo   = (const float*)d_in[8];
  const float* w1   = (const float*)d_in[9];
  const float* w2   = (const float*)d_in[10];
  const float* w3   = (const float*)d_in[11];

  char* p = (char*)d_ws;
  bf16* wqkv_t = (bf16*)p;                 p += (size_t)Nqkv * Dc * 2;   // 12.58 MB
  float* xat   = (float*)d_ws;             // aliases wqkv_t (dead by wo-gemm)
  bf16* wo_t = (bf16*)p;                   p += (size_t)Dc * Dc * 2;     // 8.39 MB
  bf16* w13t = (bf16*)p;                   p += (size_t)2 * Fc * Dc * 2; // 46.14 MB
  bf16* w2t  = w13t;                       // aliases w13t (dead after ffn)
  bf16* xn   = (bf16*)p;                   p += (size_t)Mr * Dc * 2;     // 8.39 MB (reused as h)
  bf16* ao   = (bf16*)p;                   p += (size_t)Mr * Dc * 2;     // 8.39 MB
  bf16* act  = (bf16*)p;                   p += (size_t)Mr * Fc * 2;     // 23.07 MB
  float* Pbuf = (float*)p;                 p += (size_t)4 * Mr * Dc * 4; // 67.11 MB
  bf16* hb = xn;
  // Qr/Kr/Vt alias the act region (act written only after attention is done)
  bf16* Qr = act;                                        // 8.39 MB
  bf16* Kr = act + (size_t)Mr * Hc * DHc;                // 2.10 MB
  bf16* Vtb = Kr + (size_t)Mr * HKVc * DHc;              // 2.10 MB

  const dim3 blk(256);
  tcast_k<<<dim3(32, 32), blk, 0, stream>>>(wq, wqkv_t, 2048, 2048);
  tcast_k<<<dim3(8, 32), blk, 0, stream>>>(wk, wqkv_t + (size_t)2048 * 2048, 512, 2048);
  tcast_k<<<dim3(8, 32), blk, 0, stream>>>(wv, wqkv_t + (size_t)2560 * 2048, 512, 2048);
  tcast_k<<<dim3(32, 32), blk, 0, stream>>>(wo, wo_t, 2048, 2048);
  tcast_ffn<<<dim3(88, 32), blk, 0, stream>>>(w1, w13t, 0);
  tcast_ffn<<<dim3(88, 32), blk, 0, stream>>>(w3, w13t, 16);

  rmsnorm_k<<<Mr, blk, 0, stream>>>(x, wn1, xn);
  // qkv GEMM: partials = xn @ wqkv (split-K z=2, 8-phase); reduce fused in repack
  gemm256sk<Dc, 1024><<<dim3(Nqkv / 256, Mr / 256, 2), dim3(512), 0, stream>>>(xn, wqkv_t, Pbuf, Nqkv);
  repack_k<<<Mr, blk, 0, stream>>>(Pbuf, fcos, fsin, Qr, Kr, Vtb);
  fattn<<<Bc * Hc * 16, blk, 0, stream>>>(Qr, Kr, Vtb, ao);
  // wo GEMM: partials = ao @ wo (split-K, plain f32 stores)
  gemm256sk<Dc, 512><<<dim3(Dc / 256, Mr / 256, 4), dim3(512), 0, stream>>>(ao, wo_t, Pbuf, Dc);
  // fused: xat = x + sum(partials); hb = rmsnorm(xat) * wn2
  reduce4_rms<<<Mr, blk, 0, stream>>>(Pbuf, x, wn2, xat, hb);
  ffn_gemm256<Dc><<<dim3(2 * Fc / 256, Mr / 256), dim3(512), 0, stream>>>(hb, w13t, act);
  tcast_k<<<dim3(32, 88), blk, 0, stream>>>(w2, w2t, 2048, 5632);
  // w2 GEMM: partials = act @ w2 (split-K); d_out = xat + sum(partials)
  gemm256sk<Fc, 1408><<<dim3(Dc / 256, Mr / 256, 4), dim3(512), 0, stream>>>(act, w2t, Pbuf, Dc);
  reduce4_add<<<Mr * Dc / 1024, blk, 0, stream>>>(Pbuf, xat, (float*)d_out);
}

// Round 9
// 529.739 us; speedup vs baseline: 1.2272x; 1.0590x over previous
//
#include <hip/hip_runtime.h>
#include <hip/hip_bf16.h>
#include <math.h>

typedef __hip_bfloat16 bf16;
typedef __attribute__((ext_vector_type(8))) short bf16x8;   // 8 bf16 = 4 VGPR
typedef __attribute__((ext_vector_type(4))) float f32x4;

__device__ __forceinline__ float b2f(bf16 v) { return __bfloat162float(v); }
__device__ __forceinline__ bf16  f2b(float v) { return __float2bfloat16(v); }

constexpr int Bc = 2, Tc = 1024, Dc = 2048, Hc = 16, HKVc = 4, DHc = 128, Fc = 5632;
constexpr int Mr = Bc * Tc;                      // 2048 rows
constexpr int Nqkv = Hc * DHc + 2 * HKVc * DHc;  // 3072

// async 16B global->LDS (lands at wave-uniform base + lane*16)
__device__ __forceinline__ void g2l16(void* lds, const void* g) {
  __builtin_amdgcn_global_load_lds(
      (const __attribute__((address_space(1))) unsigned int*)g,
      (__attribute__((address_space(3))) unsigned int*)lds, 16, 0, 0);
}

// ------------------------------------------------- transpose+cast tile body --
// src fp32 [K][N] row-major -> dst bf16 [N][K] row-major; one 64x64 tile.
// t in [0,256); tile = 64x68 bf16 scratch (8704 B).
__device__ __forceinline__ void tcast_tile(const float* __restrict__ src,
                                           bf16* __restrict__ dst,
                                           int N, int K, int n0, int k0,
                                           int t, bf16 (*tile)[68]) {
#pragma unroll
  for (int it = 0; it < 4; ++it) {
    const int kl = it * 16 + (t >> 4);
    const int nl = (t & 15) * 4;
    float4 v = *reinterpret_cast<const float4*>(src + (size_t)(k0 + kl) * N + n0 + nl);
    tile[kl][nl]     = f2b(v.x);
    tile[kl][nl + 1] = f2b(v.y);
    tile[kl][nl + 2] = f2b(v.z);
    tile[kl][nl + 3] = f2b(v.w);
  }
  __syncthreads();
  union { uint4 u; bf16 h[8]; } o;   // 16 B
#pragma unroll
  for (int it = 0; it < 2; ++it) {
    const int nl = it * 32 + (t >> 3);
    const int kl = (t & 7) * 8;
#pragma unroll
    for (int j = 0; j < 8; ++j) o.h[j] = tile[kl + j][nl];
    *reinterpret_cast<uint4*>(dst + (size_t)(n0 + nl) * K + k0 + kl) = o.u;
  }
}

// ---------------- transpose+cast + gate/up 16-row interleave tile (FFN) -----
// src fp32 [2048][5632]; col n -> w13t row 32*(n>>4)+(n&15)+off, stride Dc.
__device__ __forceinline__ void tcast_ffn_tile(const float* __restrict__ src,
                                               bf16* __restrict__ dst, int off,
                                               int n0, int k0, int t,
                                               bf16 (*tile)[68]) {
#pragma unroll
  for (int it = 0; it < 4; ++it) {
    const int kl = it * 16 + (t >> 4);
    const int nl = (t & 15) * 4;
    float4 v = *reinterpret_cast<const float4*>(src + (size_t)(k0 + kl) * Fc + n0 + nl);
    tile[kl][nl]     = f2b(v.x);
    tile[kl][nl + 1] = f2b(v.y);
    tile[kl][nl + 2] = f2b(v.z);
    tile[kl][nl + 3] = f2b(v.w);
  }
  __syncthreads();
  union { uint4 u; bf16 h[8]; } o;   // 16 B
#pragma unroll
  for (int it = 0; it < 2; ++it) {
    const int nl = it * 32 + (t >> 3);
    const int kl = (t & 7) * 8;
#pragma unroll
    for (int j = 0; j < 8; ++j) o.h[j] = tile[kl + j][nl];
    const int n = n0 + nl;
    const int r = ((n >> 4) << 5) + (n & 15) + off;
    *reinterpret_cast<uint4*>(dst + (size_t)r * Dc + k0 + kl) = o.u;
  }
}

// ------------------------------------------------------- RMSNorm row body ---
__device__ __forceinline__ void rmsnorm_row(const float* __restrict__ x,
                                            const float* __restrict__ w,
                                            bf16* __restrict__ out,
                                            int row, float* red) {
  const size_t rbase = (size_t)row * Dc;
  float ss = 0.f;
  for (int i = threadIdx.x; i < Dc; i += 256) {
    float v = x[rbase + i];
    ss += v * v;
  }
#pragma unroll
  for (int off = 32; off > 0; off >>= 1) ss += __shfl_down(ss, off, 64);
  const int lane = threadIdx.x & 63, wid = threadIdx.x >> 6;
  if (lane == 0) red[wid] = ss;
  __syncthreads();
  const float scale = rsqrtf((red[0] + red[1] + red[2] + red[3]) / (float)Dc + 1e-6f);
  for (int i = threadIdx.x; i < Dc; i += 256)
    out[rbase + i] = f2b(x[rbase + i] * scale * w[i]);
}

// ------ prep1: wq/wk/wv transpose+cast  +  rmsnorm(x)  (one launch) ---------
__global__ __launch_bounds__(256) void prep1(const float* __restrict__ wq,
                                             const float* __restrict__ wk,
                                             const float* __restrict__ wv,
                                             const float* __restrict__ x,
                                             const float* __restrict__ wn1,
                                             bf16* __restrict__ wqkv_t,
                                             bf16* __restrict__ xn) {
  __shared__ __align__(16) bf16 tile[64][68];
  const int b = blockIdx.x;
  if (b < 1024) {
    tcast_tile(wq, wqkv_t, 2048, 2048, (b & 31) * 64, (b >> 5) * 64, threadIdx.x, tile);
  } else if (b < 1280) {
    const int r = b - 1024;
    tcast_tile(wk, wqkv_t + (size_t)2048 * 2048, 512, 2048, (r & 7) * 64, (r >> 3) * 64, threadIdx.x, tile);
  } else if (b < 1536) {
    const int r = b - 1280;
    tcast_tile(wv, wqkv_t + (size_t)2560 * 2048, 512, 2048, (r & 7) * 64, (r >> 3) * 64, threadIdx.x, tile);
  } else {
    rmsnorm_row(x, wn1, xn, b - 1536, (float*)tile);
  }
}

// ----------------- reduce 4 split-K partials + residual + RMSNorm (fused) ---
__global__ __launch_bounds__(256) void reduce4_rms(const float* __restrict__ P,
                                                   const float* __restrict__ x,
                                                   const float* __restrict__ w,
                                                   float* __restrict__ xat,
                                                   bf16* __restrict__ hb) {
  constexpr size_t PS = (size_t)Mr * Dc;
  const size_t base4 = (size_t)blockIdx.x * (Dc / 4);
  const int t = threadIdx.x;
  float4 v[2];
  float ss = 0.f;
#pragma unroll
  for (int j = 0; j < 2; ++j) {
    const size_t c4 = base4 + t + j * 256;
    float4 a = reinterpret_cast<const float4*>(x)[c4];
#pragma unroll
    for (int z = 0; z < 4; ++z) {
      float4 q = reinterpret_cast<const float4*>(P + z * PS)[c4];
      a.x += q.x; a.y += q.y; a.z += q.z; a.w += q.w;
    }
    reinterpret_cast<float4*>(xat)[c4] = a;
    ss += a.x * a.x + a.y * a.y + a.z * a.z + a.w * a.w;
    v[j] = a;
  }
#pragma unroll
  for (int off = 32; off > 0; off >>= 1) ss += __shfl_down(ss, off, 64);
  __shared__ float red[4];
  const int lane = t & 63, wid = t >> 6;
  if (lane == 0) red[wid] = ss;
  __syncthreads();
  const float scale = rsqrtf((red[0] + red[1] + red[2] + red[3]) / (float)Dc + 1e-6f);
  bf16* hrow = hb + (size_t)blockIdx.x * Dc;
#pragma unroll
  for (int j = 0; j < 2; ++j) {
    const int c = (t + j * 256) * 4;
    hrow[c]     = f2b(v[j].x * scale * w[c]);
    hrow[c + 1] = f2b(v[j].y * scale * w[c + 1]);
    hrow[c + 2] = f2b(v[j].z * scale * w[c + 2]);
    hrow[c + 3] = f2b(v[j].w * scale * w[c + 3]);
  }
}

// --------------------- reduce 4 split-K partials + residual (final output) --
__global__ __launch_bounds__(256) void reduce4_add(const float* __restrict__ P,
                                                   const float* __restrict__ res,
                                                   float* __restrict__ out) {
  constexpr size_t PS = (size_t)Mr * Dc;
  const size_t c4 = (size_t)blockIdx.x * 256 + threadIdx.x;
  float4 a = reinterpret_cast<const float4*>(res)[c4];
#pragma unroll
  for (int z = 0; z < 4; ++z) {
    float4 q = reinterpret_cast<const float4*>(P + z * PS)[c4];
    a.x += q.x; a.y += q.y; a.z += q.z; a.w += q.w;
  }
  reinterpret_cast<float4*>(out)[c4] = a;
}

// --------------- split-K 256x256 8-phase MFMA GEMM body (T2+T3+T4+T5) ------
// Verified schedule (rounds 3-8). smem: As 64KB @0, Bs 96KB @65536.
template <int KFULL, int KSUB>
__device__ __forceinline__ void gemm256sk_dev(const bf16* __restrict__ A,
                                              const bf16* __restrict__ Bt,
                                              float* __restrict__ Part,
                                              int N, int bx, int by, int bz,
                                              char* smem) {
  constexpr int NT = KSUB / 64;
  constexpr int NIT = NT / 2;
  bf16* As = (bf16*)smem;
  bf16* Bs = (bf16*)(smem + 65536);
  const int tid = threadIdx.x;
  const int lane = tid & 63, wv = tid >> 6;
  const int wr = wv >> 2, wc = wv & 3;
  const int fr = lane & 15, quad = lane >> 4;
  const int swz = fr & 7;
  const int bm = by * 256;
  const int bn = bx * 256;
  const int kbase = bz * KSUB;
  const int lrow = tid >> 3;
  const int scol = ((tid & 7) ^ (lrow & 7)) * 8;
  const size_t rstep = (size_t)64 * KFULL;

  auto stageA = [&](int t, int half) {
    const int buf = (t & 1) * 16384;
    const bf16* g = A + (size_t)(bm + half * 128 + lrow) * KFULL + kbase + t * 64 + scol;
    bf16* d = As + buf + half * 8192 + (size_t)tid * 8;
    g2l16(d, g);
    g2l16(d + 4096, g + rstep);
  };
  auto stageB = [&](int t, int half, int buf) {
    const bf16* g = Bt + (size_t)(bn + half * 128 + lrow) * KFULL + kbase + t * 64 + scol;
    bf16* d = Bs + buf * 16384 + half * 8192 + (size_t)tid * 8;
    g2l16(d, g);
    g2l16(d + 4096, g + rstep);
  };

  f32x4 acc[8][4] = {};
  const int u0 = (quad ^ swz) * 8;

  stageA(0, 0); stageA(0, 1);
  stageB(0, 0, 0); stageB(0, 1, 0);
  stageB(1, 0, 1); stageB(1, 1, 1);
  asm volatile("s_waitcnt vmcnt(4)" ::: "memory");
  __builtin_amdgcn_s_barrier();

  int rb0 = 0, rb1 = 1, sb = 2;
  for (int it = 0; it < NIT; ++it) {
    const int t1 = 2 * it + 1;
#pragma unroll
    for (int j = 0; j < 8; ++j) {
      const int bufT = (j < 4) ? 0 : 16384;
      const int bufB = ((j < 4) ? rb0 : rb1) * 16384;
      const int qr4 = ((j & 3) >> 1) * 4, qc2 = ((j & 3) & 1) * 2;
      bf16x8 af[4][2], bv[2][2];
      const bf16* Ab = As + bufT + (size_t)(wr * 128 + fr) * 64;
      const bf16* Bb = Bs + bufB + (size_t)(wc * 64 + fr) * 64;
#pragma unroll
      for (int ii = 0; ii < 4; ++ii) {
        af[ii][0] = *reinterpret_cast<const bf16x8*>(Ab + (qr4 + ii) * 1024 + u0);
        af[ii][1] = *reinterpret_cast<const bf16x8*>(Ab + (qr4 + ii) * 1024 + (u0 ^ 32));
      }
#pragma unroll
      for (int jj = 0; jj < 2; ++jj) {
        bv[jj][0] = *reinterpret_cast<const bf16x8*>(Bb + (qc2 + jj) * 1024 + u0);
        bv[jj][1] = *reinterpret_cast<const bf16x8*>(Bb + (qc2 + jj) * 1024 + (u0 ^ 32));
      }
      if (j == 0)      stageA(t1, 0);
      else if (j == 1) stageA(t1, 1);
      else if (j == 2) { if (2 * it + 2 < NT) stageB(2 * it + 2, 0, sb); }
      else if (j == 3) { if (2 * it + 2 < NT) stageB(2 * it + 2, 1, sb); }
      else if (j == 4) { if (2 * it + 2 < NT) stageA(2 * it + 2, 0); }
      else if (j == 5) { if (2 * it + 2 < NT) stageA(2 * it + 2, 1); }
      else if (j == 6) { if (2 * it + 3 < NT) stageB(2 * it + 3, 0, rb0); }
      else             { if (2 * it + 3 < NT) stageB(2 * it + 3, 1, rb0); }
      __builtin_amdgcn_s_barrier();
      asm volatile("s_waitcnt lgkmcnt(0)" ::: "memory");
      __builtin_amdgcn_sched_barrier(0);
      __builtin_amdgcn_s_setprio(1);
#pragma unroll
      for (int ii = 0; ii < 4; ++ii)
#pragma unroll
        for (int jj = 0; jj < 2; ++jj) {
          acc[qr4 + ii][qc2 + jj] = __builtin_amdgcn_mfma_f32_16x16x32_bf16(
              af[ii][0], bv[jj][0], acc[qr4 + ii][qc2 + jj], 0, 0, 0);
          acc[qr4 + ii][qc2 + jj] = __builtin_amdgcn_mfma_f32_16x16x32_bf16(
              af[ii][1], bv[jj][1], acc[qr4 + ii][qc2 + jj], 0, 0, 0);
        }
      __builtin_amdgcn_s_setprio(0);
      if (j == 3) {
        if (2 * it + 2 < NT) asm volatile("s_waitcnt vmcnt(4)" ::: "memory");
        else                 asm volatile("s_waitcnt vmcnt(0)" ::: "memory");
      } else if (j == 7) {
        if (2 * it + 3 < NT)      asm volatile("s_waitcnt vmcnt(4)" ::: "memory");
        else if (2 * it + 2 < NT) asm volatile("s_waitcnt vmcnt(0)" ::: "memory");
      }
      __builtin_amdgcn_s_barrier();
    }
    const int nrb0 = sb; sb = rb1; rb1 = rb0; rb0 = nrb0;
  }

  float* P = Part + (size_t)bz * ((size_t)Mr * N);
  const int er = quad * 4, ec = lane & 15;
#pragma unroll
  for (int i = 0; i < 8; ++i) {
    const int row = bm + wr * 128 + i * 16 + er;
#pragma unroll
    for (int jc = 0; jc < 4; ++jc) {
      const int col = bn + wc * 64 + jc * 16 + ec;
#pragma unroll
      for (int r = 0; r < 4; ++r)
        P[(size_t)(row + r) * N + col] = acc[i][jc][r];
    }
  }
}

template <int KFULL, int KSUB>
__global__ __launch_bounds__(512, 2) void gemm256sk(const bf16* __restrict__ A,
                                                    const bf16* __restrict__ Bt,
                                                    float* __restrict__ Part,
                                                    int N) {
  __shared__ __align__(16) char smem[163840];
  gemm256sk_dev<KFULL, KSUB>(A, Bt, Part, N, blockIdx.x, blockIdx.y, blockIdx.z, smem);
}

// ------------ qkv mega: split-K qkv GEMM + wo-tcast + w1/w3-tcast -----------
// blocks [0,192): qkv gemm256sk<Dc,1024> (z=2, 12x8 tiles); dispatched first.
// [192,704): wo tcast dual-tile; [704,2112): w1; [2112,3520): w3.
// Idle CUs during the 192-block qkv wave run the tcast blocks.
__global__ __launch_bounds__(512, 2) void qkv_mega(const bf16* __restrict__ A,
                                                   const bf16* __restrict__ Bt,
                                                   float* __restrict__ Part,
                                                   const float* __restrict__ wo,
                                                   bf16* __restrict__ wo_t,
                                                   const float* __restrict__ w1,
                                                   const float* __restrict__ w3,
                                                   bf16* __restrict__ w13t) {
  __shared__ __align__(16) char smem[163840];
  const int b = blockIdx.x;
  if (b < 192) {
    gemm256sk_dev<Dc, 1024>(A, Bt, Part, Nqkv, b % 12, (b / 12) % 8, b / 96, smem);
  } else {
    const int sub = threadIdx.x >> 8, t = threadIdx.x & 255;
    bf16 (*tile)[68] = reinterpret_cast<bf16(*)[68]>(smem + sub * 8704);
    if (b < 704) {
      const int tt = (b - 192) * 2 + sub;
      tcast_tile(wo, wo_t, 2048, 2048, (tt & 31) * 64, (tt >> 5) * 64, t, tile);
    } else if (b < 2112) {
      const int tt = (b - 704) * 2 + sub;
      tcast_ffn_tile(w1, w13t, 0, (tt % 88) * 64, (tt / 88) * 64, t, tile);
    } else {
      const int tt = (b - 2112) * 2 + sub;
      tcast_ffn_tile(w3, w13t, 16, (tt % 88) * 64, (tt / 88) * 64, t, tile);
    }
  }
}

// -------------------------- FFN 256x256 8-phase MFMA GEMM body --------------
template <int K>
__device__ __forceinline__ void ffn_dev(const bf16* __restrict__ A,
                                        const bf16* __restrict__ B,
                                        bf16* __restrict__ act,
                                        int bx, int by, char* smem) {
  constexpr int NT = K / 64;
  constexpr int NIT = NT / 2;
  bf16* As = (bf16*)smem;
  bf16* Bs = (bf16*)(smem + 65536);
  const int tid = threadIdx.x;
  const int lane = tid & 63, wv = tid >> 6;
  const int wr = wv >> 2, wc = wv & 3;
  const int fr = lane & 15, quad = lane >> 4;
  const int swz = fr & 7;
  const int bm = by * 256;
  const int bn = bx * 256;
  const int lrow = tid >> 3;
  const int scol = ((tid & 7) ^ (lrow & 7)) * 8;
  const size_t rstep = (size_t)64 * K;

  auto stageA = [&](int t, int half) {
    const int buf = (t & 1) * 16384;
    const bf16* g = A + (size_t)(bm + half * 128 + lrow) * K + t * 64 + scol;
    bf16* d = As + buf + half * 8192 + (size_t)tid * 8;
    g2l16(d, g);
    g2l16(d + 4096, g + rstep);
  };
  auto stageB = [&](int t, int half, int buf) {
    const bf16* g = B + (size_t)(bn + half * 128 + lrow) * K + t * 64 + scol;
    bf16* d = Bs + buf * 16384 + half * 8192 + (size_t)tid * 8;
    g2l16(d, g);
    g2l16(d + 4096, g + rstep);
  };

  f32x4 acc[8][4] = {};
  const int u0 = (quad ^ swz) * 8;

  stageA(0, 0); stageA(0, 1);
  stageB(0, 0, 0); stageB(0, 1, 0);
  stageB(1, 0, 1); stageB(1, 1, 1);
  asm volatile("s_waitcnt vmcnt(4)" ::: "memory");
  __builtin_amdgcn_s_barrier();

  int rb0 = 0, rb1 = 1, sb = 2;
  for (int it = 0; it < NIT; ++it) {
    const int t1 = 2 * it + 1;
#pragma unroll
    for (int j = 0; j < 8; ++j) {
      const int bufT = (j < 4) ? 0 : 16384;
      const int bufB = ((j < 4) ? rb0 : rb1) * 16384;
      const int qr4 = ((j & 3) >> 1) * 4, qc2 = ((j & 3) & 1) * 2;
      bf16x8 af[4][2], bv[2][2];
      const bf16* Ab = As + bufT + (size_t)(wr * 128 + fr) * 64;
      const bf16* Bb = Bs + bufB + (size_t)(wc * 64 + fr) * 64;
#pragma unroll
      for (int ii = 0; ii < 4; ++ii) {
        af[ii][0] = *reinterpret_cast<const bf16x8*>(Ab + (qr4 + ii) * 1024 + u0);
        af[ii][1] = *reinterpret_cast<const bf16x8*>(Ab + (qr4 + ii) * 1024 + (u0 ^ 32));
      }
#pragma unroll
      for (int jj = 0; jj < 2; ++jj) {
        bv[jj][0] = *reinterpret_cast<const bf16x8*>(Bb + (qc2 + jj) * 1024 + u0);
        bv[jj][1] = *reinterpret_cast<const bf16x8*>(Bb + (qc2 + jj) * 1024 + (u0 ^ 32));
      }
      if (j == 0)      stageA(t1, 0);
      else if (j == 1) stageA(t1, 1);
      else if (j == 2) { if (2 * it + 2 < NT) stageB(2 * it + 2, 0, sb); }
      else if (j == 3) { if (2 * it + 2 < NT) stageB(2 * it + 2, 1, sb); }
      else if (j == 4) { if (2 * it + 2 < NT) stageA(2 * it + 2, 0); }
      else if (j == 5) { if (2 * it + 2 < NT) stageA(2 * it + 2, 1); }
      else if (j == 6) { if (2 * it + 3 < NT) stageB(2 * it + 3, 0, rb0); }
      else             { if (2 * it + 3 < NT) stageB(2 * it + 3, 1, rb0); }
      __builtin_amdgcn_s_barrier();
      asm volatile("s_waitcnt lgkmcnt(0)" ::: "memory");
      __builtin_amdgcn_sched_barrier(0);
      __builtin_amdgcn_s_setprio(1);
#pragma unroll
      for (int ii = 0; ii < 4; ++ii)
#pragma unroll
        for (int jj = 0; jj < 2; ++jj) {
          acc[qr4 + ii][qc2 + jj] = __builtin_amdgcn_mfma_f32_16x16x32_bf16(
              af[ii][0], bv[jj][0], acc[qr4 + ii][qc2 + jj], 0, 0, 0);
          acc[qr4 + ii][qc2 + jj] = __builtin_amdgcn_mfma_f32_16x16x32_bf16(
              af[ii][1], bv[jj][1], acc[qr4 + ii][qc2 + jj], 0, 0, 0);
        }
      __builtin_amdgcn_s_setprio(0);
      if (j == 3) {
        if (2 * it + 2 < NT) asm volatile("s_waitcnt vmcnt(4)" ::: "memory");
        else                 asm volatile("s_waitcnt vmcnt(0)" ::: "memory");
      } else if (j == 7) {
        if (2 * it + 3 < NT)      asm volatile("s_waitcnt vmcnt(4)" ::: "memory");
        else if (2 * it + 2 < NT) asm volatile("s_waitcnt vmcnt(0)" ::: "memory");
      }
      __builtin_amdgcn_s_barrier();
    }
    const int nrb0 = sb; sb = rb1; rb1 = rb0; rb0 = nrb0;
  }

  const int er = quad * 4, ec = lane & 15;
#pragma unroll
  for (int i = 0; i < 8; ++i) {
    const int row = bm + wr * 128 + i * 16 + er;
#pragma unroll
    for (int jp = 0; jp < 2; ++jp) {
      const f32x4 g = acc[i][2 * jp], u = acc[i][2 * jp + 1];
      const int f = bx * 128 + wc * 32 + jp * 16 + ec;
#pragma unroll
      for (int r = 0; r < 4; ++r) {
        const float sg = g[r] / (1.f + __expf(-g[r]));
        act[(size_t)(row + r) * Fc + f] = f2b(sg * u[r]);
      }
    }
  }
}

// ------------ ffn mega: ffn GEMM (352 blocks) + optional w2-tcast tail ------
__global__ __launch_bounds__(512, 2) void ffn_mega(const bf16* __restrict__ A,
                                                   const bf16* __restrict__ B,
                                                   bf16* __restrict__ act,
                                                   const float* __restrict__ w2,
                                                   bf16* __restrict__ w2t) {
  __shared__ __align__(16) char smem[163840];
  const int b = blockIdx.x;
  if (b < 352) {
    ffn_dev<Dc>(A, B, act, b % 44, b / 44, smem);
  } else {
    const int sub = threadIdx.x >> 8, t = threadIdx.x & 255;
    bf16 (*tile)[68] = reinterpret_cast<bf16(*)[68]>(smem + sub * 8704);
    const int tt = (b - 352) * 2 + sub;      // 2816 tiles, grid (32,88)
    tcast_tile(w2, w2t, 2048, 5632, (tt & 31) * 64, (tt >> 5) * 64, t, tile);
  }
}

// ------------------- standalone tcast (fallback for w2 only) ----------------
__global__ __launch_bounds__(256) void tcast_k(const float* __restrict__ src,
                                               bf16* __restrict__ dst,
                                               int N, int K) {
  __shared__ __align__(16) bf16 tile[64][68];
  tcast_tile(src, dst, N, K, blockIdx.x * 64, blockIdx.y * 64, threadIdx.x, tile);
}

// ------------------- repack: reduce 2 qkv partials + RoPE + Q/K/V split -----
__global__ __launch_bounds__(256) void repack_k(const float* __restrict__ P,
                                                const float* __restrict__ cosb,
                                                const float* __restrict__ sinb,
                                                bf16* __restrict__ Qr,
                                                bf16* __restrict__ Kr,
                                                bf16* __restrict__ Vt) {
  constexpr size_t PS = (size_t)Mr * Nqkv;
  const int bt = blockIdx.x;
  const int b = bt >> 10, tp = bt & (Tc - 1);
  const int t0 = threadIdx.x;
  const float* r0 = P + (size_t)bt * Nqkv;
  const float* r1 = r0 + PS;
#pragma unroll
  for (int k = 0; k < 4; ++k) {      // Q: 1024 rope pairs
    int p2 = k * 256 + t0;
    int hh = p2 >> 6, i = p2 & 63;
    float c = cosb[tp * 64 + i], sn = sinb[tp * 64 + i];
    float2 v0 = *reinterpret_cast<const float2*>(r0 + hh * 128 + 2 * i);
    float2 v1 = *reinterpret_cast<const float2*>(r1 + hh * 128 + 2 * i);
    float x0 = v0.x + v1.x, x1 = v0.y + v1.y;
    bf16* dst = Qr + ((size_t)(b * Hc + hh) * Tc + tp) * DHc + 2 * i;
    dst[0] = f2b(x0 * c - x1 * sn);
    dst[1] = f2b(x0 * sn + x1 * c);
  }
  {                                   // K: 256 rope pairs
    int hh = t0 >> 6, i = t0 & 63;
    float c = cosb[tp * 64 + i], sn = sinb[tp * 64 + i];
    float2 v0 = *reinterpret_cast<const float2*>(r0 + 2048 + hh * 128 + 2 * i);
    float2 v1 = *reinterpret_cast<const float2*>(r1 + 2048 + hh * 128 + 2 * i);
    float x0 = v0.x + v1.x, x1 = v0.y + v1.y;
    bf16* dst = Kr + ((size_t)(b * HKVc + hh) * Tc + tp) * DHc + 2 * i;
    dst[0] = f2b(x0 * c - x1 * sn);
    dst[1] = f2b(x0 * sn + x1 * c);
  }
#pragma unroll
  for (int k = 0; k < 2; ++k) {      // V: 512 elems, transposed store
    int e = k * 256 + t0;
    int kvh = e >> 7, dd = e & 127;
    Vt[((size_t)(b * HKVc + kvh) * DHc + dd) * Tc + tp] = f2b(r0[2560 + e] + r1[2560 + e]);
  }
}

// ----------------------------------------------------- MFMA flash attention --
// (round-8 verified: async dbuf K/V staging, swizzled, 1 barrier/tile)
__global__ __launch_bounds__(256) void fattn(const bf16* __restrict__ Qr,
                                             const bf16* __restrict__ Kr,
                                             const bf16* __restrict__ Vt,
                                             bf16* __restrict__ ao) {
  __shared__ __align__(16) bf16 Ks[2][64 * 128];   // [key][d], linear, swz
  __shared__ __align__(16) bf16 Vts[2][128 * 64];  // [d][key], linear, swz
  __shared__ __align__(16) bf16 Ps[4][16 * 72];    // per-wave P
  const int idx = blockIdx.x;
  const int r = idx & 15;
  const int qt = (r & 1) ? (15 - (r >> 1)) : (r >> 1);  // pair-balanced
  const int h = (idx >> 4) & 15;
  const int b = idx >> 8;
  const int kv = h >> 2;
  const int t = threadIdx.x, lane = t & 63, wv = t >> 6;
  const int fr = lane & 15, quad = lane >> 4;

  const bf16* Qbase = Qr + ((size_t)(b * Hc + h) * Tc + qt * 64) * DHc;
  const bf16* Kbase = Kr + (size_t)(b * HKVc + kv) * Tc * DHc;
  const bf16* Vbase = Vt + (size_t)(b * HKVc + kv) * DHc * Tc;

  auto stageK = [&](int kt, int buf) {
    const bf16* src = Kbase + (size_t)kt * 64 * DHc;
#pragma unroll
    for (int rr = 0; rr < 4; ++rr) {
      const int row = rr * 16 + (t >> 4);
      const int cS = (t & 15) ^ (row & 7);
      g2l16(&Ks[buf][rr * 2048 + t * 8], src + row * DHc + cS * 8);
    }
  };
  auto stageV = [&](int kt, int buf) {
#pragma unroll
    for (int rr = 0; rr < 4; ++rr) {
      const int row = rr * 32 + (t >> 3);
      const int cS = (t & 7) ^ (row & 7);
      g2l16(&Vts[buf][rr * 2048 + t * 8], Vbase + (size_t)row * Tc + kt * 64 + cS * 8);
    }
  };

  bf16x8 qf[4];
#pragma unroll
  for (int c = 0; c < 4; ++c)
    qf[c] = *reinterpret_cast<const bf16x8*>(Qbase + (size_t)(wv * 16 + fr) * DHc + c * 32 + quad * 8);

  float m[4], l[4];
  f32x4 o[8] = {};
#pragma unroll
  for (int r2 = 0; r2 < 4; ++r2) { m[r2] = -3.0e38f; l[r2] = 0.f; }

  stageK(0, 0);
  stageV(0, 0);
  __syncthreads();
  int buf = 0;

  for (int kt = 0; kt <= qt; ++kt) {
    if (kt < qt) { stageK(kt + 1, buf ^ 1); stageV(kt + 1, buf ^ 1); }
    const int sw = fr & 7;
    f32x4 s[4];
    __builtin_amdgcn_s_setprio(1);
#pragma unroll
    for (int cb = 0; cb < 4; ++cb) {
      f32x4 acc = {};
#pragma unroll
      for (int kc = 0; kc < 4; ++kc) {
        bf16x8 kf = *reinterpret_cast<const bf16x8*>(
            &Ks[buf][(cb * 16 + fr) * 128 + (((kc << 2) + quad) ^ sw) * 8]);
        acc = __builtin_amdgcn_mfma_f32_16x16x32_bf16(qf[kc], kf, acc, 0, 0, 0);
      }
      s[cb] = acc * 0.08838834764831845f;
    }
    __builtin_amdgcn_s_setprio(0);
    if (kt == qt) {
#pragma unroll
      for (int cb = 0; cb < 4; ++cb)
#pragma unroll
        for (int r2 = 0; r2 < 4; ++r2) {
          int key = cb * 16 + fr;
          int qg = wv * 16 + quad * 4 + r2;
          if (key > qg) s[cb][r2] = -3.0e38f;
        }
    }
    float tm[4], ts[4];
#pragma unroll
    for (int r2 = 0; r2 < 4; ++r2)
      tm[r2] = fmaxf(fmaxf(s[0][r2], s[1][r2]), fmaxf(s[2][r2], s[3][r2]));
#pragma unroll
    for (int off = 1; off < 16; off <<= 1)
#pragma unroll
      for (int r2 = 0; r2 < 4; ++r2)
        tm[r2] = fmaxf(tm[r2], __shfl_xor(tm[r2], off, 64));
    float al[4];
#pragma unroll
    for (int r2 = 0; r2 < 4; ++r2) {
      float mn = fmaxf(m[r2], tm[r2]);
      al[r2] = __expf(m[r2] - mn);
      m[r2] = mn;
      ts[r2] = 0.f;
    }
#pragma unroll
    for (int cb = 0; cb < 4; ++cb)
#pragma unroll
      for (int r2 = 0; r2 < 4; ++r2) {
        float e = __expf(s[cb][r2] - m[r2]);
        s[cb][r2] = e;
        ts[r2] += e;
      }
#pragma unroll
    for (int off = 1; off < 16; off <<= 1)
#pragma unroll
      for (int r2 = 0; r2 < 4; ++r2)
        ts[r2] += __shfl_xor(ts[r2], off, 64);
#pragma unroll
    for (int r2 = 0; r2 < 4; ++r2) l[r2] = l[r2] * al[r2] + ts[r2];
#pragma unroll
    for (int db = 0; db < 8; ++db)
#pragma unroll
      for (int r2 = 0; r2 < 4; ++r2) o[db][r2] *= al[r2];
    bf16* pw = Ps[wv];
#pragma unroll
    for (int cb = 0; cb < 4; ++cb)
#pragma unroll
      for (int r2 = 0; r2 < 4; ++r2)
        pw[(quad * 4 + r2) * 72 + cb * 16 + fr] = f2b(s[cb][r2]);
    bf16x8 pa[2];
    pa[0] = *reinterpret_cast<const bf16x8*>(&pw[fr * 72 + quad * 8]);
    pa[1] = *reinterpret_cast<const bf16x8*>(&pw[fr * 72 + 32 + quad * 8]);
    __builtin_amdgcn_s_setprio(1);
#pragma unroll
    for (int db = 0; db < 8; ++db) {
      bf16x8 v0 = *reinterpret_cast<const bf16x8*>(
          &Vts[buf][(db * 16 + fr) * 64 + (quad ^ sw) * 8]);
      bf16x8 v1 = *reinterpret_cast<const bf16x8*>(
          &Vts[buf][(db * 16 + fr) * 64 + ((4 + quad) ^ sw) * 8]);
      o[db] = __builtin_amdgcn_mfma_f32_16x16x32_bf16(pa[0], v0, o[db], 0, 0, 0);
      o[db] = __builtin_amdgcn_mfma_f32_16x16x32_bf16(pa[1], v1, o[db], 0, 0, 0);
    }
    __builtin_amdgcn_s_setprio(0);
    __syncthreads();
    buf ^= 1;
  }
#pragma unroll
  for (int r2 = 0; r2 < 4; ++r2) {
    float inv = 1.f / l[r2];
    int qg = qt * 64 + wv * 16 + quad * 4 + r2;
    bf16* orow = ao + (size_t)(b * Tc + qg) * Dc + h * DHc;
#pragma unroll
    for (int db = 0; db < 8; ++db)
      orow[db * 16 + fr] = f2b(o[db][r2] * inv);
  }
}

// ------------------------------------------------------------------ launch --
extern "C" void kernel_launch(void* const* d_in, const int* in_sizes, int n_in,
                              void* d_out, int out_size, void* d_ws, size_t ws_size,
                              hipStream_t stream) {
  const float* x    = (const float*)d_in[0];
  const float* fcos = (const float*)d_in[1];
  const float* fsin = (const float*)d_in[2];
  const float* wn1  = (const float*)d_in[3];
  const float* wn2  = (const float*)d_in[4];
  const float* wq   = (const float*)d_in[5];
  const float* wk   = (const float*)d_in[6];
  const float* wv   = (const float*)d_in[7];
  const float* wo   = (const float*)d_in[8];
  const float* w1   = (const float*)d_in[9];
  const float* w2   = (const float*)d_in[10];
  const float* w3   = (const float*)d_in[11];

  char* p = (char*)d_ws;
  bf16* wqkv_t = (bf16*)p;                 p += (size_t)Nqkv * Dc * 2;   // 12.58 MB
  float* xat   = (float*)d_ws;             // aliases wqkv_t (+4.2MB of wo_t; both dead then)
  bf16* wo_t = (bf16*)p;                   p += (size_t)Dc * Dc * 2;     // 8.39 MB
  bf16* w13t = (bf16*)p;                   p += (size_t)2 * Fc * Dc * 2; // 46.14 MB
  bf16* xn   = (bf16*)p;                   p += (size_t)Mr * Dc * 2;     // 8.39 MB (reused as h)
  bf16* ao   = (bf16*)p;                   p += (size_t)Mr * Dc * 2;     // 8.39 MB
  bf16* act  = (bf16*)p;                   p += (size_t)Mr * Fc * 2;     // 23.07 MB
  float* Pbuf = (float*)p;                 p += (size_t)4 * Mr * Dc * 4; // 67.11 MB
  bf16* hb = xn;
  // Qr/Kr/Vt alias the act region (act written only after attention is done)
  bf16* Qr = act;
  bf16* Kr = act + (size_t)Mr * Hc * DHc;
  bf16* Vtb = Kr + (size_t)Mr * HKVc * DHc;
  // w2t: own region if workspace allows (needed for ffn||w2-tcast overlap);
  // else alias w13t and tcast serially after ffn.
  const size_t w2t_bytes = (size_t)Dc * Fc * 2;                          // 23.07 MB
  const size_t base_used = (size_t)(p - (char*)d_ws);
  const bool fused_w2 = (ws_size >= base_used + w2t_bytes);
  bf16* w2t = fused_w2 ? (bf16*)p : w13t;

  const dim3 blk(256);
  // 1: wq/wk/wv tcast + rmsnorm
  prep1<<<3584, blk, 0, stream>>>(wq, wk, wv, x, wn1, wqkv_t, xn);
  // 2: qkv split-K GEMM (192 blocks) + wo/w1/w3 tcasts filling idle CUs
  qkv_mega<<<3520, dim3(512), 0, stream>>>(xn, wqkv_t, Pbuf, wo, wo_t, w1, w3, w13t);
  // 3: reduce qkv partials + RoPE + repack
  repack_k<<<Mr, blk, 0, stream>>>(Pbuf, fcos, fsin, Qr, Kr, Vtb);
  // 4: flash attention
  fattn<<<Bc * Hc * 16, blk, 0, stream>>>(Qr, Kr, Vtb, ao);
  // 5: wo GEMM (split-K, 256 blocks = exactly one CU wave)
  gemm256sk<Dc, 512><<<dim3(Dc / 256, Mr / 256, 4), dim3(512), 0, stream>>>(ao, wo_t, Pbuf, Dc);
  // 6: xat = x + sum(partials); hb = rmsnorm(xat)
  reduce4_rms<<<Mr, blk, 0, stream>>>(Pbuf, x, wn2, xat, hb);
  // 7: FFN GEMM (352 blocks) + w2-tcast filling the 31% tail
  if (fused_w2) {
    ffn_mega<<<352 + 1408, dim3(512), 0, stream>>>(hb, w13t, act, w2, w2t);
  } else {
    ffn_mega<<<352, dim3(512), 0, stream>>>(hb, w13t, act, w2, w2t);
    tcast_k<<<dim3(32, 88), blk, 0, stream>>>(w2, w2t, 2048, 5632);
  }
  // 8: w2 GEMM (split-K); 9: d_out = xat + sum(partials)
  gemm256sk<Fc, 1408><<<dim3(Dc / 256, Mr / 256, 4), dim3(512), 0, stream>>>(act, w2t, Pbuf, Dc);
  reduce4_add<<<Mr * Dc / 1024, blk, 0, stream>>>(Pbuf, xat, (float*)d_out);
}